// Round 1
// baseline (280.676 us; speedup 1.0000x reference)
//
#include <hip/hip_runtime.h>
#include <hip/hip_bf16.h>

#define NG 100000
#define NU 100000
#define NE 3200000
#define NC 2000000

// dst-bucket binning: 128 dsts per bucket
#define BSZ 128
#define NBK 782          // ceil(NG/BSZ)
#define CAP 5120         // entries per fine bucket (mean 4096, +16 sigma)

// two-level binning: 61 super-buckets of 13 fine buckets (61*13=793>=782)
#define NSUP 61
#define SFB 13
#define SSPAN (SFB * BSZ)   // 1664 dsts per super
#define SCAP 56320          // entries per super (mean 52459, +17 sigma)
#define B1CH 4096           // edges per bin1 block (LDS-staged single read)
#define B2CH 4096           // entries per bin2 block

typedef __attribute__((ext_vector_type(8))) short short8;
typedef __attribute__((ext_vector_type(4))) float floatx4;
typedef unsigned short ushortx8 __attribute__((ext_vector_type(8)));

// branchless SELU on the HW transcendental (6 VALU ops)
__device__ __forceinline__ float selu_f(float x) {
    const float LAM = 1.0507009873554805f;
    const float ALA = 1.7580993408473766f;  // LAM * ALPHA
    const float L2E = 1.44269504088896340736f;
    float e = __builtin_amdgcn_exp2f(fminf(x, 0.f) * L2E);
    return fmaf(LAM, fmaxf(x, 0.f), fmaf(ALA, e, -ALA));
}

__device__ __forceinline__ float bfbits2f(unsigned short u) {
    return __uint_as_float(((unsigned)u) << 16);
}

__device__ __forceinline__ unsigned short f2bfbits(float f) {
    union { __hip_bfloat16 h; unsigned short u; } cv;
    cv.h = __float2bfloat16(f);
    return cv.u;
}

__device__ __forceinline__ float ldf(const void* p, int i, int isbf) {
    return isbf ? bfbits2f(((const unsigned short*)p)[i]) : ((const float*)p)[i];
}

// ---- dtype detection ------------------------------------------------------
__global__ void k_detect(const unsigned int* __restrict__ xw,
                         const unsigned int* __restrict__ cw,
                         const unsigned int* __restrict__ ew,
                         int* __restrict__ flags) {
    if (threadIdx.x != 0 || blockIdx.x != 0) return;
    int nb = 0;
    for (int i = 0; i < 64; ++i) {
        unsigned lo = xw[i] & 0xffffu;
        unsigned e = (lo >> 7) & 0xff;
        if (e >= 112 && e <= 134) ++nb;
    }
    flags[0] = (nb >= 32) ? 1 : 0;
    int cz = 0, ez = 0;
    for (int i = 0; i < 64; ++i) {
        if (cw[2 * i + 1] == 0u) ++cz;
        if (ew[2 * i + 1] == 0u) ++ez;
    }
    flags[1] = (cz >= 48) ? 1 : 0;
    flags[2] = (ez >= 48) ? 1 : 0;
}

__device__ __forceinline__ void ld_edge(const void* edges, long long e, int e64,
                                        int& s, int& d) {
    if (e64) {
        const long long* el = (const long long*)edges;
        s = (int)el[e];
        d = (int)el[NE + e];
    } else {
        const int* ei = (const int*)edges;
        s = ei[e];
        d = ei[NE + e];
    }
}

// ---- Binning pass 1: edges -> 61 super-buckets. SINGLE global read:
//      entries staged in LDS during the histogram pass. Runs ~67 entries
//      (268 B) at 61 buckets -> still fully coalesced writes. --------------
__global__ __launch_bounds__(256) void k_bin1(const void* __restrict__ edges,
        int* __restrict__ scur, unsigned int* __restrict__ slist,
        const int* __restrict__ flags) {
    __shared__ unsigned int tmp[B1CH];         // 16 KB  (s<<11)|dlocal
    __shared__ unsigned char tsup[B1CH];       // 4 KB
    __shared__ unsigned int ord[B1CH];         // 16 KB
    __shared__ unsigned char osup[B1CH];       // 4 KB
    __shared__ int hist[64];
    __shared__ int lstart[64];
    __shared__ int ofs[64];
    __shared__ int gbase[64];                  // ~41 KB -> 3 blocks/CU

    int tid = threadIdx.x;
    long long base = (long long)blockIdx.x * B1CH;
    int chunk = (int)(NE - base);
    if (chunk > B1CH) chunk = B1CH;
    int e64 = flags[2];

    if (tid < 64) hist[tid] = 0;
    __syncthreads();

    // phase A: single global read -> LDS stage + histogram
    for (int i = 0; i < B1CH / 256; ++i) {
        int idx = i * 256 + tid;
        if (idx < chunk) {
            int s, d;
            ld_edge(edges, base + idx, e64, s, d);
            int sup = d / SSPAN;
            tmp[idx] = ((unsigned)s << 11) | (unsigned)(d - sup * SSPAN);
            tsup[idx] = (unsigned char)sup;
            atomicAdd(&hist[sup], 1);
        }
    }
    __syncthreads();

    // phase B: serial scan (61) + global reservation
    if (tid == 0) {
        int run = 0;
        for (int b = 0; b < NSUP; ++b) {
            lstart[b] = run;
            run += hist[b];
        }
    }
    __syncthreads();
    if (tid < NSUP) {
        int c = hist[tid];
        int g = 0;
        if (c > 0) g = atomicAdd(&scur[tid], c);
        gbase[tid] = g;
        ofs[tid] = lstart[tid];
    }
    __syncthreads();

    // phase C: reorder within LDS
    for (int i = 0; i < B1CH / 256; ++i) {
        int idx = i * 256 + tid;
        if (idx < chunk) {
            int sup = tsup[idx];
            int pos = atomicAdd(&ofs[sup], 1);
            ord[pos] = tmp[idx];
            osup[pos] = (unsigned char)sup;
        }
    }
    __syncthreads();

    // phase D: coalesced write-out
    for (int i = 0; i < B1CH / 256; ++i) {
        int idx = i * 256 + tid;
        if (idx < chunk) {
            int sup = osup[idx];
            int p = gbase[sup] + (idx - lstart[sup]);
            if (p < SCAP) slist[(long long)sup * SCAP + p] = ord[idx];
        }
    }
}

#define SCH2 ((SCAP + B2CH - 1) / B2CH)   // 14 chunks per super

// ---- Binning pass 2: super -> 13 fine buckets. SINGLE slist read. --------
__global__ __launch_bounds__(256) void k_bin2(const int* __restrict__ scur,
        const unsigned int* __restrict__ slist,
        int* __restrict__ gcur, unsigned int* __restrict__ glist) {
    __shared__ unsigned int tmp[B2CH];         // 16 KB
    __shared__ unsigned int ord[B2CH];         // 16 KB
    __shared__ unsigned char ofid[B2CH];       // 4 KB
    __shared__ int hist[16];
    __shared__ int lstart[16];
    __shared__ int ofs[16];
    __shared__ int gbase[16];                  // ~36.5 KB -> 4 blocks/CU

    int tid = threadIdx.x;
    int sup = blockIdx.x / SCH2;
    int ch = blockIdx.x % SCH2;
    int scnt = scur[sup];
    if (scnt > SCAP) scnt = SCAP;
    int start = ch * B2CH;
    int cnt = scnt - start;
    if (cnt <= 0) return;
    if (cnt > B2CH) cnt = B2CH;
    const unsigned int* sp = slist + (long long)sup * SCAP + start;

    if (tid < 16) hist[tid] = 0;
    __syncthreads();

    // phase A: single global read -> LDS stage + histogram
    for (int i = 0; i < B2CH / 256; ++i) {
        int idx = i * 256 + tid;
        if (idx < cnt) {
            unsigned u = sp[idx];
            tmp[idx] = u;
            atomicAdd(&hist[(u & 2047) >> 7], 1);
        }
    }
    __syncthreads();

    if (tid == 0) {
        int run = 0;
        for (int b = 0; b < SFB; ++b) {
            lstart[b] = run;
            run += hist[b];
        }
    }
    __syncthreads();
    if (tid < SFB) {
        int c = hist[tid];
        int g = 0;
        int bf = sup * SFB + tid;
        if (c > 0 && bf < NBK) g = atomicAdd(&gcur[bf], c);
        gbase[tid] = g;
        ofs[tid] = lstart[tid];
    }
    __syncthreads();

    // phase C: reorder within LDS (convert to (s<<7)|dl127)
    for (int i = 0; i < B2CH / 256; ++i) {
        int idx = i * 256 + tid;
        if (idx < cnt) {
            unsigned u = tmp[idx];
            int dl = u & 2047;
            int f = dl >> 7;
            int pos = atomicAdd(&ofs[f], 1);
            ord[pos] = ((u >> 11) << 7) | (unsigned)(dl & 127);
            ofid[pos] = (unsigned char)f;
        }
    }
    __syncthreads();

    // phase D: coalesced write-out (runs ~315 entries)
    for (int i = 0; i < B2CH / 256; ++i) {
        int idx = i * 256 + tid;
        if (idx < cnt) {
            int f = ofid[idx];
            int bf = sup * SFB + f;
            int p = gbase[f] + (idx - lstart[f]);
            if (p < CAP) glist[(long long)bf * CAP + p] = ord[idx];
        }
    }
}

// ---- Counting-sort each bucket by dl. SINGLE glist read (LDS-staged),
//      in-place write-back; emits per-dst CSR. -----------------------------
__global__ __launch_bounds__(256) void k_sort(const int* __restrict__ gcur,
        unsigned int* __restrict__ glist,
        int* __restrict__ dstoff, int* __restrict__ ddeg) {
    __shared__ unsigned int tmp[CAP];      // 20 KB
    __shared__ unsigned int sorted[CAP];   // 20 KB
    __shared__ int hist[BSZ];
    __shared__ int incl[BSZ];
    __shared__ int cur[BSZ];               // ~41.5 KB -> 3 blocks/CU
    int b = blockIdx.x;
    int tid = threadIdx.x;
    int cnt = gcur[b];
    if (cnt > CAP) cnt = CAP;
    unsigned int* lp = glist + (long long)b * CAP;

    if (tid < BSZ) hist[tid] = 0;
    __syncthreads();
    // single global read -> LDS + histogram
    for (int k = tid; k < cnt; k += 256) {
        unsigned u = lp[k];
        tmp[k] = u;
        atomicAdd(&hist[u & 127], 1);
    }
    __syncthreads();
    if (tid < BSZ) incl[tid] = hist[tid];
    __syncthreads();
    for (int off = 1; off < BSZ; off <<= 1) {
        int v = (tid < BSZ && tid >= off) ? incl[tid - off] : 0;
        __syncthreads();
        if (tid < BSZ && tid >= off) incl[tid] += v;
        __syncthreads();
    }
    if (tid < BSZ) {
        int excl = incl[tid] - hist[tid];
        cur[tid] = excl;
        int d = b * BSZ + tid;
        if (d < NG) {
            dstoff[d] = b * CAP + excl;
            ddeg[d] = hist[tid];
        }
    }
    __syncthreads();
    for (int k = tid; k < cnt; k += 256) {
        unsigned u = tmp[k];
        int pos = atomicAdd(&cur[u & 127], 1);
        sorted[pos] = u >> 7;
    }
    __syncthreads();
    for (int k = tid; k < cnt; k += 256) lp[k] = sorted[k];
}

// ---- Gather+Node 1 fused: 16 threads/dst, paired independent gathers ------
__global__ __launch_bounds__(256) void k_gather1(const int* __restrict__ dstoff,
        const int* __restrict__ ddeg, const unsigned int* __restrict__ glist,
        const void* __restrict__ xg,
        const void* __restrict__ W1r, const void* __restrict__ W1o,
        const void* __restrict__ b1, unsigned short* __restrict__ hbf,
        const int* __restrict__ flags) {
    int gid = blockIdx.x * 256 + threadIdx.x;
    int d = gid >> 4;
    if (d >= NG) return;
    int q = gid & 15;
    int isbf = flags[0];
    int start = dstoff[d];
    int deg = ddeg[d];
    float a0 = 0.f, a1 = 0.f, a2 = 0.f, a3 = 0.f;
    int k = q;
    for (; k + 16 < deg; k += 32) {
        int s0 = glist[start + k];
        int s1 = glist[start + k + 16];
        if (isbf) {
            ushort4 r0 = *(const ushort4*)((const unsigned short*)xg + s0 * 4);
            ushort4 r1 = *(const ushort4*)((const unsigned short*)xg + s1 * 4);
            a0 += bfbits2f(r0.x) + bfbits2f(r1.x);
            a1 += bfbits2f(r0.y) + bfbits2f(r1.y);
            a2 += bfbits2f(r0.z) + bfbits2f(r1.z);
            a3 += bfbits2f(r0.w) + bfbits2f(r1.w);
        } else {
            float4 r0 = *(const float4*)((const float*)xg + s0 * 4);
            float4 r1 = *(const float4*)((const float*)xg + s1 * 4);
            a0 += r0.x + r1.x;
            a1 += r0.y + r1.y;
            a2 += r0.z + r1.z;
            a3 += r0.w + r1.w;
        }
    }
    for (; k < deg; k += 16) {
        int s = glist[start + k];
        if (isbf) {
            ushort4 r = *(const ushort4*)((const unsigned short*)xg + s * 4);
            a0 += bfbits2f(r.x); a1 += bfbits2f(r.y);
            a2 += bfbits2f(r.z); a3 += bfbits2f(r.w);
        } else {
            float4 r = *(const float4*)((const float*)xg + s * 4);
            a0 += r.x; a1 += r.y; a2 += r.z; a3 += r.w;
        }
    }
#pragma unroll
    for (int off = 1; off < 16; off <<= 1) {
        a0 += __shfl_xor(a0, off);
        a1 += __shfl_xor(a1, off);
        a2 += __shfl_xor(a2, off);
        a3 += __shfl_xor(a3, off);
    }
    if (q < 8) {
        float a[4] = {a0, a1, a2, a3};
        float v = ldf(b1, q, isbf);
#pragma unroll
        for (int c = 0; c < 4; ++c)
            v += a[c] * ldf(W1r, c * 8 + q, isbf)
               + ldf(xg, d * 4 + c, isbf) * ldf(W1o, c * 8 + q, isbf);
        hbf[d * 8 + q] = f2bfbits(selu_f(v));
    }
}

// ---- Gather+Node 2 fused: 16 threads/dst; lane q -> output j=q ------------
__global__ __launch_bounds__(256) void k_gather2(const int* __restrict__ dstoff,
        const int* __restrict__ ddeg, const unsigned int* __restrict__ glist,
        const ushortx8* __restrict__ hbf,
        const void* __restrict__ W2r, const void* __restrict__ W2o,
        const void* __restrict__ b2, unsigned short* __restrict__ xs,
        const int* __restrict__ flags) {
    int gid = blockIdx.x * 256 + threadIdx.x;
    int d = gid >> 4;
    if (d >= NG) return;
    int q = gid & 15;
    int isbf = flags[0];
    int start = dstoff[d];
    int deg = ddeg[d];
    float a[8] = {0.f, 0.f, 0.f, 0.f, 0.f, 0.f, 0.f, 0.f};
    int k = q;
    for (; k + 16 < deg; k += 32) {
        int s0 = glist[start + k];
        int s1 = glist[start + k + 16];
        ushortx8 r0 = hbf[s0];
        ushortx8 r1 = hbf[s1];
#pragma unroll
        for (int c = 0; c < 8; ++c)
            a[c] += bfbits2f((unsigned short)r0[c]) + bfbits2f((unsigned short)r1[c]);
    }
    for (; k < deg; k += 16) {
        int s = glist[start + k];
        ushortx8 r = hbf[s];
#pragma unroll
        for (int c = 0; c < 8; ++c) a[c] += bfbits2f((unsigned short)r[c]);
    }
#pragma unroll
    for (int off = 1; off < 16; off <<= 1) {
#pragma unroll
        for (int c = 0; c < 8; ++c) a[c] += __shfl_xor(a[c], off);
    }
    ushortx8 hr = hbf[d];
    float hv[8];
#pragma unroll
    for (int c = 0; c < 8; ++c) hv[c] = bfbits2f((unsigned short)hr[c]);
    float v = ldf(b2, q, isbf);
#pragma unroll
    for (int c = 0; c < 8; ++c)
        v += a[c] * ldf(W2r, c * 16 + q, isbf)
           + hv[c] * ldf(W2o, c * 16 + q, isbf);
    xs[d * 16 + q] = f2bfbits(selu_f(v));
}

// ---- fc_unconnected -> x_stacked[NG:NG+NU] (bf16), NO selu ----------------
__global__ __launch_bounds__(256) void k_unconn(const void* __restrict__ xu,
        const void* __restrict__ Wun, const void* __restrict__ bun,
        unsigned short* __restrict__ xs, const int* __restrict__ flags) {
    int u = blockIdx.x * 256 + threadIdx.x;
    if (u >= NU) return;
    int isbf = flags[0];
    float x[4];
#pragma unroll
    for (int k = 0; k < 4; ++k) x[k] = ldf(xu, u * 4 + k, isbf);
    ushortx8 lo, hi;
#pragma unroll
    for (int j = 0; j < 16; ++j) {
        float v = ldf(bun, j, isbf);
#pragma unroll
        for (int k = 0; k < 4; ++k)
            v += x[k] * ldf(Wun, k * 16 + j, isbf);
        unsigned short bb = f2bfbits(v);
        if (j < 8) lo[j] = bb; else hi[j - 8] = bb;
    }
    ushortx8* xp = (ushortx8*)(xs + (NG + u) * 16);
    xp[0] = lo;
    xp[1] = hi;
}

__device__ __forceinline__ int2 ld_cand2(const void* cand, int c, int c64) {
    if (c64) {
        const long long* cl = (const long long*)cand;
        return make_int2((int)cl[2 * c], (int)cl[2 * c + 1]);
    }
    return *(const int2*)((const int*)cand + 2 * c);
}

// ---- FC head: persistent waves, software-pipelined gather.
//      TRANSPOSED MFMA: A = W1^T fragment (identical bytes to the old B
//      fragment -- A/B layouts are index-identical), B = candidate fragment
//      (identical bytes to the old A fragment). Output: col = candidate,
//      row = hidden. Bias rides in the MFMA C operand; SELU is folded into
//      the fc2 dot:  w2*selu(v) = (w2*LAM)*max(v,0) + (w2*ALA)*exp2(min(v,0)*L2E)
//                                 - w2*ALA   (constant, folded into c_corr).
//      Reduce is 2 shfl+2 add on one scalar (was 16 shfl + 32 add on 4). ---
__global__ __launch_bounds__(256) void k_fc(const unsigned short* __restrict__ xs,
        const void* __restrict__ cand,
        const void* __restrict__ Wfc1, const void* __restrict__ bfc1,
        const void* __restrict__ Wfc2, const void* __restrict__ bfc2,
        void* __restrict__ out, const int* __restrict__ flags) {
    const float LAM = 1.0507009873554805f;
    const float ALA = 1.7580993408473766f;  // LAM * ALPHA
    const float L2E = 1.44269504088896340736f;
    int lane = threadIdx.x & 63;
    int wid = (blockIdx.x * blockDim.x + threadIdx.x) >> 6;
    int m = lane & 15;
    int half = lane >> 4;
    int isbf = flags[0], c64 = flags[1];

    // W1 fragment (A operand): A[row = hidden tt*16+m, k = half*8+j] = W1[k][h]
    short8 wfrag[4];
#pragma unroll
    for (int t = 0; t < 4; ++t) {
#pragma unroll
        for (int j = 0; j < 8; ++j)
            wfrag[t][j] = (short)f2bfbits(ldf(Wfc1, (half * 8 + j) * 64 + t * 16 + m, isbf));
    }
    // per-lane hidden units of the transposed output: h = tt*16 + half*4 + r
    floatx4 cbias[4];
    float w2L[4][4], w2A[4][4];
#pragma unroll
    for (int t = 0; t < 4; ++t) {
#pragma unroll
        for (int r = 0; r < 4; ++r) {
            int h = t * 16 + half * 4 + r;
            cbias[t][r] = ldf(bfc1, h, isbf);
            float w2 = ldf(Wfc2, h, isbf);
            w2L[t][r] = w2 * LAM;
            w2A[t][r] = w2 * ALA;
        }
    }
    float sumw2 = 0.f;
    for (int h = 0; h < 64; ++h) sumw2 += ldf(Wfc2, h, isbf);
    float c_corr = ldf(bfc2, 0, isbf) - ALA * sumw2;

    const int nTiles = NC / 16;
    int nW = (gridDim.x * blockDim.x) >> 6;
    if (wid >= nTiles) return;

    int tn1 = wid + nW;
    int2 cc_cur = ld_cand2(cand, wid * 16 + m, c64);
    int tn1c = (tn1 < nTiles) ? tn1 : wid;
    int2 cc_nxt = ld_cand2(cand, tn1c * 16 + m, c64);
    {
        int row = (half < 2) ? cc_cur.x : cc_cur.y;
        short8 af_cur = *(const short8*)(xs + row * 16 + (half & 1) * 8);

        for (int t = wid; t < nTiles; t += nW) {
            int tnn = t + 2 * nW;
            int tnnc = (tnn < nTiles) ? tnn : t;
            int2 cc_n2 = ld_cand2(cand, tnnc * 16 + m, c64);
            int rown = (half < 2) ? cc_nxt.x : cc_nxt.y;
            short8 af_nxt = *(const short8*)(xs + rown * 16 + (half & 1) * 8);

            float part = 0.f;
#pragma unroll
            for (int tt = 0; tt < 4; ++tt) {
                floatx4 ac = __builtin_amdgcn_mfma_f32_16x16x32_bf16(
                    wfrag[tt], af_cur, cbias[tt], 0, 0, 0);
#pragma unroll
                for (int r = 0; r < 4; ++r) {
                    float v = ac[r];
                    float e = __builtin_amdgcn_exp2f(fminf(v, 0.f) * L2E);
                    part = fmaf(w2L[tt][r], fmaxf(v, 0.f), part);
                    part = fmaf(w2A[tt][r], e, part);
                }
            }
            part += __shfl_xor(part, 16, 64);
            part += __shfl_xor(part, 32, 64);
            if (half == 0) {
                float o = part + c_corr;
                if (isbf) ((unsigned short*)out)[t * 16 + m] = f2bfbits(o);
                else ((float*)out)[t * 16 + m] = o;
            }
            cc_nxt = cc_n2;
            af_cur = af_nxt;
        }
    }
}

extern "C" void kernel_launch(void* const* d_in, const int* in_sizes, int n_in,
                              void* d_out, int out_size, void* d_ws, size_t ws_size,
                              hipStream_t stream) {
    const void* x_u = d_in[0];
    const void* x_g = d_in[1];
    const void* cand = d_in[2];
    const void* edges = d_in[3];
    const void* W1r = d_in[4];
    const void* W1o = d_in[5];
    const void* b1 = d_in[6];
    const void* W2r = d_in[7];
    const void* W2o = d_in[8];
    const void* b2 = d_in[9];
    const void* Wun = d_in[10];
    const void* bun = d_in[11];
    const void* Wfc1 = d_in[12];
    const void* bfc1 = d_in[13];
    const void* Wfc2 = d_in[14];
    const void* bfc2 = d_in[15];

    char* ws = (char*)d_ws;
    int* flags = (int*)ws;                                  // 64 B
    int* gcur = (int*)(ws + 64);                            // 782*4 -> 3200 B
    int* scur = (int*)(ws + 3264);                          // 61*4  -> 244 B
    unsigned int* glist = (unsigned int*)(ws + 4160);       // 16.01 MB
    size_t glist_bytes = (size_t)NBK * CAP * 4;             // 16010240
    char* p = ws + 4160 + glist_bytes;
    // slist (13.75 MB) overlaps the post-binning buffers: dead after k_bin2.
    unsigned int* slist = (unsigned int*)p;                 // 61*56320*4 = 13.74 MB
    int* dstoff = (int*)p;                                  // 400 KB
    int* ddeg = (int*)(p + 400000);                         // 400 KB
    unsigned short* hbf = (unsigned short*)(p + 800000);    // 1.6 MB
    unsigned short* xs = (unsigned short*)(p + 2400000);    // 6.4 MB

    hipMemsetAsync(gcur, 0, 3456, stream);   // zeroes gcur + scur

    k_detect<<<1, 64, 0, stream>>>((const unsigned int*)x_u,
                                   (const unsigned int*)cand,
                                   (const unsigned int*)edges, flags);
    k_bin1<<<(NE + B1CH - 1) / B1CH, 256, 0, stream>>>(edges, scur, slist, flags);
    k_bin2<<<NSUP * SCH2, 256, 0, stream>>>(scur, slist, gcur, glist);
    k_sort<<<NBK, 256, 0, stream>>>(gcur, glist, dstoff, ddeg);
    k_gather1<<<(16 * NG + 255) / 256, 256, 0, stream>>>(dstoff, ddeg, glist, x_g,
                                                         W1r, W1o, b1, hbf, flags);
    k_gather2<<<(16 * NG + 255) / 256, 256, 0, stream>>>(dstoff, ddeg, glist,
                                                         (const ushortx8*)hbf,
                                                         W2r, W2o, b2, xs, flags);
    k_unconn<<<(NU + 255) / 256, 256, 0, stream>>>(x_u, Wun, bun, xs, flags);
    k_fc<<<2048, 256, 0, stream>>>(xs, cand, Wfc1, bfc1, Wfc2, bfc2, d_out, flags);
}

// Round 2
// 274.940 us; speedup vs baseline: 1.0209x; 1.0209x over previous
//
#include <hip/hip_runtime.h>
#include <hip/hip_bf16.h>

#define NG 100000
#define NU 100000
#define NE 3200000
#define NC 2000000

// dst-bucket binning: 128 dsts per bucket
#define BSZ 128
#define NBK 782          // ceil(NG/BSZ)
#define CAP 5120         // entries per fine bucket (mean 4096, +16 sigma)

// two-level binning: 61 super-buckets of 13 fine buckets (61*13=793>=782)
#define NSUP 61
#define SFB 13
#define SSPAN (SFB * BSZ)   // 1664 dsts per super
#define SCAP 56320          // entries per super (mean 52459, +17 sigma)
#define B1CH 4096           // edges per bin1 block (LDS-staged single read)
#define B2CH 4096           // entries per bin2 block

typedef __attribute__((ext_vector_type(8))) short short8;
typedef __attribute__((ext_vector_type(4))) float floatx4;
typedef unsigned short ushortx8 __attribute__((ext_vector_type(8)));

// branchless SELU on the HW transcendental (6 VALU ops)
__device__ __forceinline__ float selu_f(float x) {
    const float LAM = 1.0507009873554805f;
    const float ALA = 1.7580993408473766f;  // LAM * ALPHA
    const float L2E = 1.44269504088896340736f;
    float e = __builtin_amdgcn_exp2f(fminf(x, 0.f) * L2E);
    return fmaf(LAM, fmaxf(x, 0.f), fmaf(ALA, e, -ALA));
}

__device__ __forceinline__ float bfbits2f(unsigned short u) {
    return __uint_as_float(((unsigned)u) << 16);
}

__device__ __forceinline__ unsigned short f2bfbits(float f) {
    union { __hip_bfloat16 h; unsigned short u; } cv;
    cv.h = __float2bfloat16(f);
    return cv.u;
}

__device__ __forceinline__ float ldf(const void* p, int i, int isbf) {
    return isbf ? bfbits2f(((const unsigned short*)p)[i]) : ((const float*)p)[i];
}

// ---- dtype detection ------------------------------------------------------
__global__ void k_detect(const unsigned int* __restrict__ xw,
                         const unsigned int* __restrict__ cw,
                         const unsigned int* __restrict__ ew,
                         int* __restrict__ flags) {
    if (threadIdx.x != 0 || blockIdx.x != 0) return;
    int nb = 0;
    for (int i = 0; i < 64; ++i) {
        unsigned lo = xw[i] & 0xffffu;
        unsigned e = (lo >> 7) & 0xff;
        if (e >= 112 && e <= 134) ++nb;
    }
    flags[0] = (nb >= 32) ? 1 : 0;
    int cz = 0, ez = 0;
    for (int i = 0; i < 64; ++i) {
        if (cw[2 * i + 1] == 0u) ++cz;
        if (ew[2 * i + 1] == 0u) ++ez;
    }
    flags[1] = (cz >= 48) ? 1 : 0;
    flags[2] = (ez >= 48) ? 1 : 0;
}

__device__ __forceinline__ void ld_edge(const void* edges, long long e, int e64,
                                        int& s, int& d) {
    if (e64) {
        const long long* el = (const long long*)edges;
        s = (int)el[e];
        d = (int)el[NE + e];
    } else {
        const int* ei = (const int*)edges;
        s = ei[e];
        d = ei[NE + e];
    }
}

// ---- Binning pass 1: edges -> 61 super-buckets. SINGLE global read:
//      entries staged in LDS during the histogram pass. Runs ~67 entries
//      (268 B) at 61 buckets -> still fully coalesced writes. --------------
__global__ __launch_bounds__(256) void k_bin1(const void* __restrict__ edges,
        int* __restrict__ scur, unsigned int* __restrict__ slist,
        const int* __restrict__ flags) {
    __shared__ unsigned int tmp[B1CH];         // 16 KB  (s<<11)|dlocal
    __shared__ unsigned char tsup[B1CH];       // 4 KB
    __shared__ unsigned int ord[B1CH];         // 16 KB
    __shared__ unsigned char osup[B1CH];       // 4 KB
    __shared__ int hist[64];
    __shared__ int lstart[64];
    __shared__ int ofs[64];
    __shared__ int gbase[64];                  // ~41 KB -> 3 blocks/CU

    int tid = threadIdx.x;
    long long base = (long long)blockIdx.x * B1CH;
    int chunk = (int)(NE - base);
    if (chunk > B1CH) chunk = B1CH;
    int e64 = flags[2];

    if (tid < 64) hist[tid] = 0;
    __syncthreads();

    // phase A: single global read -> LDS stage + histogram
    for (int i = 0; i < B1CH / 256; ++i) {
        int idx = i * 256 + tid;
        if (idx < chunk) {
            int s, d;
            ld_edge(edges, base + idx, e64, s, d);
            int sup = d / SSPAN;
            tmp[idx] = ((unsigned)s << 11) | (unsigned)(d - sup * SSPAN);
            tsup[idx] = (unsigned char)sup;
            atomicAdd(&hist[sup], 1);
        }
    }
    __syncthreads();

    // phase B: serial scan (61) + global reservation
    if (tid == 0) {
        int run = 0;
        for (int b = 0; b < NSUP; ++b) {
            lstart[b] = run;
            run += hist[b];
        }
    }
    __syncthreads();
    if (tid < NSUP) {
        int c = hist[tid];
        int g = 0;
        if (c > 0) g = atomicAdd(&scur[tid], c);
        gbase[tid] = g;
        ofs[tid] = lstart[tid];
    }
    __syncthreads();

    // phase C: reorder within LDS
    for (int i = 0; i < B1CH / 256; ++i) {
        int idx = i * 256 + tid;
        if (idx < chunk) {
            int sup = tsup[idx];
            int pos = atomicAdd(&ofs[sup], 1);
            ord[pos] = tmp[idx];
            osup[pos] = (unsigned char)sup;
        }
    }
    __syncthreads();

    // phase D: coalesced write-out
    for (int i = 0; i < B1CH / 256; ++i) {
        int idx = i * 256 + tid;
        if (idx < chunk) {
            int sup = osup[idx];
            int p = gbase[sup] + (idx - lstart[sup]);
            if (p < SCAP) slist[(long long)sup * SCAP + p] = ord[idx];
        }
    }
}

#define SCH2 ((SCAP + B2CH - 1) / B2CH)   // 14 chunks per super

// ---- Binning pass 2: super -> 13 fine buckets. SINGLE slist read. --------
__global__ __launch_bounds__(256) void k_bin2(const int* __restrict__ scur,
        const unsigned int* __restrict__ slist,
        int* __restrict__ gcur, unsigned int* __restrict__ glist) {
    __shared__ unsigned int tmp[B2CH];         // 16 KB
    __shared__ unsigned int ord[B2CH];         // 16 KB
    __shared__ unsigned char ofid[B2CH];       // 4 KB
    __shared__ int hist[16];
    __shared__ int lstart[16];
    __shared__ int ofs[16];
    __shared__ int gbase[16];                  // ~36.5 KB -> 4 blocks/CU

    int tid = threadIdx.x;
    int sup = blockIdx.x / SCH2;
    int ch = blockIdx.x % SCH2;
    int scnt = scur[sup];
    if (scnt > SCAP) scnt = SCAP;
    int start = ch * B2CH;
    int cnt = scnt - start;
    if (cnt <= 0) return;
    if (cnt > B2CH) cnt = B2CH;
    const unsigned int* sp = slist + (long long)sup * SCAP + start;

    if (tid < 16) hist[tid] = 0;
    __syncthreads();

    // phase A: single global read -> LDS stage + histogram
    for (int i = 0; i < B2CH / 256; ++i) {
        int idx = i * 256 + tid;
        if (idx < cnt) {
            unsigned u = sp[idx];
            tmp[idx] = u;
            atomicAdd(&hist[(u & 2047) >> 7], 1);
        }
    }
    __syncthreads();

    if (tid == 0) {
        int run = 0;
        for (int b = 0; b < SFB; ++b) {
            lstart[b] = run;
            run += hist[b];
        }
    }
    __syncthreads();
    if (tid < SFB) {
        int c = hist[tid];
        int g = 0;
        int bf = sup * SFB + tid;
        if (c > 0 && bf < NBK) g = atomicAdd(&gcur[bf], c);
        gbase[tid] = g;
        ofs[tid] = lstart[tid];
    }
    __syncthreads();

    // phase C: reorder within LDS (convert to (s<<7)|dl127)
    for (int i = 0; i < B2CH / 256; ++i) {
        int idx = i * 256 + tid;
        if (idx < cnt) {
            unsigned u = tmp[idx];
            int dl = u & 2047;
            int f = dl >> 7;
            int pos = atomicAdd(&ofs[f], 1);
            ord[pos] = ((u >> 11) << 7) | (unsigned)(dl & 127);
            ofid[pos] = (unsigned char)f;
        }
    }
    __syncthreads();

    // phase D: coalesced write-out (runs ~315 entries)
    for (int i = 0; i < B2CH / 256; ++i) {
        int idx = i * 256 + tid;
        if (idx < cnt) {
            int f = ofid[idx];
            int bf = sup * SFB + f;
            int p = gbase[f] + (idx - lstart[f]);
            if (p < CAP) glist[(long long)bf * CAP + p] = ord[idx];
        }
    }
}

// ---- Counting-sort each bucket by dl. SINGLE glist read (LDS-staged),
//      in-place write-back; emits per-dst CSR. -----------------------------
__global__ __launch_bounds__(256) void k_sort(const int* __restrict__ gcur,
        unsigned int* __restrict__ glist,
        int* __restrict__ dstoff, int* __restrict__ ddeg) {
    __shared__ unsigned int tmp[CAP];      // 20 KB
    __shared__ unsigned int sorted[CAP];   // 20 KB
    __shared__ int hist[BSZ];
    __shared__ int incl[BSZ];
    __shared__ int cur[BSZ];               // ~41.5 KB -> 3 blocks/CU
    int b = blockIdx.x;
    int tid = threadIdx.x;
    int cnt = gcur[b];
    if (cnt > CAP) cnt = CAP;
    unsigned int* lp = glist + (long long)b * CAP;

    if (tid < BSZ) hist[tid] = 0;
    __syncthreads();
    // single global read -> LDS + histogram
    for (int k = tid; k < cnt; k += 256) {
        unsigned u = lp[k];
        tmp[k] = u;
        atomicAdd(&hist[u & 127], 1);
    }
    __syncthreads();
    if (tid < BSZ) incl[tid] = hist[tid];
    __syncthreads();
    for (int off = 1; off < BSZ; off <<= 1) {
        int v = (tid < BSZ && tid >= off) ? incl[tid - off] : 0;
        __syncthreads();
        if (tid < BSZ && tid >= off) incl[tid] += v;
        __syncthreads();
    }
    if (tid < BSZ) {
        int excl = incl[tid] - hist[tid];
        cur[tid] = excl;
        int d = b * BSZ + tid;
        if (d < NG) {
            dstoff[d] = b * CAP + excl;
            ddeg[d] = hist[tid];
        }
    }
    __syncthreads();
    for (int k = tid; k < cnt; k += 256) {
        unsigned u = tmp[k];
        int pos = atomicAdd(&cur[u & 127], 1);
        sorted[pos] = u >> 7;
    }
    __syncthreads();
    for (int k = tid; k < cnt; k += 256) lp[k] = sorted[k];
}

// ---- Gather+Node 1 fused: 16 threads/dst, paired independent gathers ------
__global__ __launch_bounds__(256) void k_gather1(const int* __restrict__ dstoff,
        const int* __restrict__ ddeg, const unsigned int* __restrict__ glist,
        const void* __restrict__ xg,
        const void* __restrict__ W1r, const void* __restrict__ W1o,
        const void* __restrict__ b1, unsigned short* __restrict__ hbf,
        const int* __restrict__ flags) {
    int gid = blockIdx.x * 256 + threadIdx.x;
    int d = gid >> 4;
    if (d >= NG) return;
    int q = gid & 15;
    int isbf = flags[0];
    int start = dstoff[d];
    int deg = ddeg[d];
    float a0 = 0.f, a1 = 0.f, a2 = 0.f, a3 = 0.f;
    int k = q;
    for (; k + 16 < deg; k += 32) {
        int s0 = glist[start + k];
        int s1 = glist[start + k + 16];
        if (isbf) {
            ushort4 r0 = *(const ushort4*)((const unsigned short*)xg + s0 * 4);
            ushort4 r1 = *(const ushort4*)((const unsigned short*)xg + s1 * 4);
            a0 += bfbits2f(r0.x) + bfbits2f(r1.x);
            a1 += bfbits2f(r0.y) + bfbits2f(r1.y);
            a2 += bfbits2f(r0.z) + bfbits2f(r1.z);
            a3 += bfbits2f(r0.w) + bfbits2f(r1.w);
        } else {
            float4 r0 = *(const float4*)((const float*)xg + s0 * 4);
            float4 r1 = *(const float4*)((const float*)xg + s1 * 4);
            a0 += r0.x + r1.x;
            a1 += r0.y + r1.y;
            a2 += r0.z + r1.z;
            a3 += r0.w + r1.w;
        }
    }
    for (; k < deg; k += 16) {
        int s = glist[start + k];
        if (isbf) {
            ushort4 r = *(const ushort4*)((const unsigned short*)xg + s * 4);
            a0 += bfbits2f(r.x); a1 += bfbits2f(r.y);
            a2 += bfbits2f(r.z); a3 += bfbits2f(r.w);
        } else {
            float4 r = *(const float4*)((const float*)xg + s * 4);
            a0 += r.x; a1 += r.y; a2 += r.z; a3 += r.w;
        }
    }
#pragma unroll
    for (int off = 1; off < 16; off <<= 1) {
        a0 += __shfl_xor(a0, off);
        a1 += __shfl_xor(a1, off);
        a2 += __shfl_xor(a2, off);
        a3 += __shfl_xor(a3, off);
    }
    if (q < 8) {
        float a[4] = {a0, a1, a2, a3};
        float v = ldf(b1, q, isbf);
#pragma unroll
        for (int c = 0; c < 4; ++c)
            v += a[c] * ldf(W1r, c * 8 + q, isbf)
               + ldf(xg, d * 4 + c, isbf) * ldf(W1o, c * 8 + q, isbf);
        hbf[d * 8 + q] = f2bfbits(selu_f(v));
    }
}

// ---- Gather+Node 2 fused: 16 threads/dst; lane q -> output j=q ------------
__global__ __launch_bounds__(256) void k_gather2(const int* __restrict__ dstoff,
        const int* __restrict__ ddeg, const unsigned int* __restrict__ glist,
        const ushortx8* __restrict__ hbf,
        const void* __restrict__ W2r, const void* __restrict__ W2o,
        const void* __restrict__ b2, unsigned short* __restrict__ xs,
        const int* __restrict__ flags) {
    int gid = blockIdx.x * 256 + threadIdx.x;
    int d = gid >> 4;
    if (d >= NG) return;
    int q = gid & 15;
    int isbf = flags[0];
    int start = dstoff[d];
    int deg = ddeg[d];
    float a[8] = {0.f, 0.f, 0.f, 0.f, 0.f, 0.f, 0.f, 0.f};
    int k = q;
    for (; k + 16 < deg; k += 32) {
        int s0 = glist[start + k];
        int s1 = glist[start + k + 16];
        ushortx8 r0 = hbf[s0];
        ushortx8 r1 = hbf[s1];
#pragma unroll
        for (int c = 0; c < 8; ++c)
            a[c] += bfbits2f((unsigned short)r0[c]) + bfbits2f((unsigned short)r1[c]);
    }
    for (; k < deg; k += 16) {
        int s = glist[start + k];
        ushortx8 r = hbf[s];
#pragma unroll
        for (int c = 0; c < 8; ++c) a[c] += bfbits2f((unsigned short)r[c]);
    }
#pragma unroll
    for (int off = 1; off < 16; off <<= 1) {
#pragma unroll
        for (int c = 0; c < 8; ++c) a[c] += __shfl_xor(a[c], off);
    }
    ushortx8 hr = hbf[d];
    float hv[8];
#pragma unroll
    for (int c = 0; c < 8; ++c) hv[c] = bfbits2f((unsigned short)hr[c]);
    float v = ldf(b2, q, isbf);
#pragma unroll
    for (int c = 0; c < 8; ++c)
        v += a[c] * ldf(W2r, c * 16 + q, isbf)
           + hv[c] * ldf(W2o, c * 16 + q, isbf);
    xs[d * 16 + q] = f2bfbits(selu_f(v));
}

// ---- fc_unconnected -> x_stacked[NG:NG+NU] (bf16), NO selu ----------------
__global__ __launch_bounds__(256) void k_unconn(const void* __restrict__ xu,
        const void* __restrict__ Wun, const void* __restrict__ bun,
        unsigned short* __restrict__ xs, const int* __restrict__ flags) {
    int u = blockIdx.x * 256 + threadIdx.x;
    if (u >= NU) return;
    int isbf = flags[0];
    float x[4];
#pragma unroll
    for (int k = 0; k < 4; ++k) x[k] = ldf(xu, u * 4 + k, isbf);
    ushortx8 lo, hi;
#pragma unroll
    for (int j = 0; j < 16; ++j) {
        float v = ldf(bun, j, isbf);
#pragma unroll
        for (int k = 0; k < 4; ++k)
            v += x[k] * ldf(Wun, k * 16 + j, isbf);
        unsigned short bb = f2bfbits(v);
        if (j < 8) lo[j] = bb; else hi[j - 8] = bb;
    }
    ushortx8* xp = (ushortx8*)(xs + (NG + u) * 16);
    xp[0] = lo;
    xp[1] = hi;
}

__device__ __forceinline__ int2 ld_cand2(const void* cand, int c, int c64) {
    if (c64) {
        const long long* cl = (const long long*)cand;
        return make_int2((int)cl[2 * c], (int)cl[2 * c + 1]);
    }
    return *(const int2*)((const int*)cand + 2 * c);
}

// ---- FC head: persistent waves, 2-deep software-pipelined gather.
//      TRANSPOSED MFMA: A = W1^T fragment, B = candidate fragment; output
//      col = candidate (lane&15), row = hidden. Bias rides in the MFMA C
//      operand; SELU folded into the fc2 dot:
//        w2*selu(v) = (w2*LAM)*max(v,0) + (w2*ALA)*exp2(min(v,0)*L2E) - w2*ALA
//      with the constant summed once into c_corr. Prologue: one wave-uniform
//      isbf branch (no per-call dual-path ldf); bf16 path copies raw W bits
//      (bf16->f32->bf16 RNE is identity); sumw2 via in-register partial +
//      2 shfl_xor (lanes hold disjoint h across `half`; m-lanes duplicate). -
__global__ __launch_bounds__(256) void k_fc(const unsigned short* __restrict__ xs,
        const void* __restrict__ cand,
        const void* __restrict__ Wfc1, const void* __restrict__ bfc1,
        const void* __restrict__ Wfc2, const void* __restrict__ bfc2,
        void* __restrict__ out, const int* __restrict__ flags) {
    const float LAM = 1.0507009873554805f;
    const float ALA = 1.7580993408473766f;  // LAM * ALPHA
    const float L2E = 1.44269504088896340736f;
    int lane = threadIdx.x & 63;
    int wid = (blockIdx.x * blockDim.x + threadIdx.x) >> 6;
    int m = lane & 15;
    int half = lane >> 4;
    int isbf = flags[0], c64 = flags[1];

    short8 wfrag[4];
    floatx4 cbias[4];
    float w2L[4][4], w2A[4][4];
    float c_corr;
    if (isbf) {
        const unsigned short* W1p = (const unsigned short*)Wfc1;
#pragma unroll
        for (int t = 0; t < 4; ++t)
#pragma unroll
            for (int j = 0; j < 8; ++j)
                wfrag[t][j] = (short)W1p[(half * 8 + j) * 64 + t * 16 + m];
        const unsigned short* b1p = (const unsigned short*)bfc1;
        const unsigned short* w2p = (const unsigned short*)Wfc2;
        float asum = 0.f;
#pragma unroll
        for (int t = 0; t < 4; ++t)
#pragma unroll
            for (int r = 0; r < 4; ++r) {
                int h = t * 16 + half * 4 + r;
                cbias[t][r] = bfbits2f(b1p[h]);
                float w2 = bfbits2f(w2p[h]);
                w2L[t][r] = w2 * LAM;
                w2A[t][r] = w2 * ALA;
                asum += w2A[t][r];
            }
        asum += __shfl_xor(asum, 16, 64);
        asum += __shfl_xor(asum, 32, 64);
        c_corr = bfbits2f(((const unsigned short*)bfc2)[0]) - asum;
    } else {
        const float* W1p = (const float*)Wfc1;
#pragma unroll
        for (int t = 0; t < 4; ++t)
#pragma unroll
            for (int j = 0; j < 8; ++j)
                wfrag[t][j] = (short)f2bfbits(W1p[(half * 8 + j) * 64 + t * 16 + m]);
        const float* b1p = (const float*)bfc1;
        const float* w2p = (const float*)Wfc2;
        float asum = 0.f;
#pragma unroll
        for (int t = 0; t < 4; ++t)
#pragma unroll
            for (int r = 0; r < 4; ++r) {
                int h = t * 16 + half * 4 + r;
                cbias[t][r] = b1p[h];
                float w2 = w2p[h];
                w2L[t][r] = w2 * LAM;
                w2A[t][r] = w2 * ALA;
                asum += w2A[t][r];
            }
        asum += __shfl_xor(asum, 16, 64);
        asum += __shfl_xor(asum, 32, 64);
        c_corr = ((const float*)bfc2)[0] - asum;
    }

    const int nTiles = NC / 16;
    int nW = (gridDim.x * blockDim.x) >> 6;
    if (wid >= nTiles) return;

    // 2-deep gather pipeline: af for tiles t, t+nW in flight; cand 3 ahead.
    int t1 = wid + nW, t2 = wid + 2 * nW;
    int2 cc0 = ld_cand2(cand, wid * 16 + m, c64);
    int2 cc1 = ld_cand2(cand, ((t1 < nTiles) ? t1 : wid) * 16 + m, c64);
    int2 cc2 = ld_cand2(cand, ((t2 < nTiles) ? t2 : wid) * 16 + m, c64);
    int half1 = half & 1;
    {
        int row0 = (half < 2) ? cc0.x : cc0.y;
        short8 af0 = *(const short8*)(xs + row0 * 16 + half1 * 8);
        int row1 = (half < 2) ? cc1.x : cc1.y;
        short8 af1 = *(const short8*)(xs + row1 * 16 + half1 * 8);

        for (int t = wid; t < nTiles; t += nW) {
            int tn3 = t + 3 * nW;
            int2 cc3 = ld_cand2(cand, ((tn3 < nTiles) ? tn3 : t) * 16 + m, c64);
            int row2 = (half < 2) ? cc2.x : cc2.y;
            short8 af2 = *(const short8*)(xs + row2 * 16 + half1 * 8);

            float part = 0.f;
#pragma unroll
            for (int tt = 0; tt < 4; ++tt) {
                floatx4 ac = __builtin_amdgcn_mfma_f32_16x16x32_bf16(
                    wfrag[tt], af0, cbias[tt], 0, 0, 0);
#pragma unroll
                for (int r = 0; r < 4; ++r) {
                    float v = ac[r];
                    float e = __builtin_amdgcn_exp2f(fminf(v, 0.f) * L2E);
                    part = fmaf(w2L[tt][r], fmaxf(v, 0.f), part);
                    part = fmaf(w2A[tt][r], e, part);
                }
            }
            part += __shfl_xor(part, 16, 64);
            part += __shfl_xor(part, 32, 64);
            if (half == 0) {
                float o = part + c_corr;
                if (isbf) ((unsigned short*)out)[t * 16 + m] = f2bfbits(o);
                else ((float*)out)[t * 16 + m] = o;
            }
            af0 = af1;
            af1 = af2;
            cc2 = cc3;
        }
    }
}

extern "C" void kernel_launch(void* const* d_in, const int* in_sizes, int n_in,
                              void* d_out, int out_size, void* d_ws, size_t ws_size,
                              hipStream_t stream) {
    const void* x_u = d_in[0];
    const void* x_g = d_in[1];
    const void* cand = d_in[2];
    const void* edges = d_in[3];
    const void* W1r = d_in[4];
    const void* W1o = d_in[5];
    const void* b1 = d_in[6];
    const void* W2r = d_in[7];
    const void* W2o = d_in[8];
    const void* b2 = d_in[9];
    const void* Wun = d_in[10];
    const void* bun = d_in[11];
    const void* Wfc1 = d_in[12];
    const void* bfc1 = d_in[13];
    const void* Wfc2 = d_in[14];
    const void* bfc2 = d_in[15];

    char* ws = (char*)d_ws;
    int* flags = (int*)ws;                                  // 64 B
    int* gcur = (int*)(ws + 64);                            // 782*4 -> 3200 B
    int* scur = (int*)(ws + 3264);                          // 61*4  -> 244 B
    unsigned int* glist = (unsigned int*)(ws + 4160);       // 16.01 MB
    size_t glist_bytes = (size_t)NBK * CAP * 4;             // 16010240
    char* p = ws + 4160 + glist_bytes;
    // slist (13.75 MB) overlaps the post-binning buffers: dead after k_bin2.
    unsigned int* slist = (unsigned int*)p;                 // 61*56320*4 = 13.74 MB
    int* dstoff = (int*)p;                                  // 400 KB
    int* ddeg = (int*)(p + 400000);                         // 400 KB
    unsigned short* hbf = (unsigned short*)(p + 800000);    // 1.6 MB
    unsigned short* xs = (unsigned short*)(p + 2400000);    // 6.4 MB

    hipMemsetAsync(gcur, 0, 3456, stream);   // zeroes gcur + scur

    k_detect<<<1, 64, 0, stream>>>((const unsigned int*)x_u,
                                   (const unsigned int*)cand,
                                   (const unsigned int*)edges, flags);
    k_bin1<<<(NE + B1CH - 1) / B1CH, 256, 0, stream>>>(edges, scur, slist, flags);
    k_bin2<<<NSUP * SCH2, 256, 0, stream>>>(scur, slist, gcur, glist);
    k_sort<<<NBK, 256, 0, stream>>>(gcur, glist, dstoff, ddeg);
    k_gather1<<<(16 * NG + 255) / 256, 256, 0, stream>>>(dstoff, ddeg, glist, x_g,
                                                         W1r, W1o, b1, hbf, flags);
    k_gather2<<<(16 * NG + 255) / 256, 256, 0, stream>>>(dstoff, ddeg, glist,
                                                         (const ushortx8*)hbf,
                                                         W2r, W2o, b2, xs, flags);
    k_unconn<<<(NU + 255) / 256, 256, 0, stream>>>(x_u, Wun, bun, xs, flags);
    k_fc<<<2048, 256, 0, stream>>>(xs, cand, Wfc1, bfc1, Wfc2, bfc2, d_out, flags);
}

// Round 3
// 272.969 us; speedup vs baseline: 1.0282x; 1.0072x over previous
//
#include <hip/hip_runtime.h>
#include <hip/hip_bf16.h>

#define NG 100000
#define NU 100000
#define NE 3200000
#define NC 2000000

// dst-bucket binning: 128 dsts per bucket
#define BSZ 128
#define NBK 782          // ceil(NG/BSZ)
#define CAP 5120         // entries per fine bucket (mean 4096, +16 sigma)

// two-level binning: 61 super-buckets of 13 fine buckets (61*13=793>=782)
#define NSUP 61
#define SFB 13
#define SSPAN (SFB * BSZ)   // 1664 dsts per super
#define SCAP 56320          // entries per super (mean 52459, +17 sigma)
#define B1CH 4096           // edges per bin1 block (LDS-staged single read)
#define B2CH 4096           // entries per bin2 block

typedef __attribute__((ext_vector_type(8))) short short8;
typedef __attribute__((ext_vector_type(4))) float floatx4;
typedef unsigned short ushortx8 __attribute__((ext_vector_type(8)));

// branchless SELU on the HW transcendental (6 VALU ops)
__device__ __forceinline__ float selu_f(float x) {
    const float LAM = 1.0507009873554805f;
    const float ALA = 1.7580993408473766f;  // LAM * ALPHA
    const float L2E = 1.44269504088896340736f;
    float e = __builtin_amdgcn_exp2f(fminf(x, 0.f) * L2E);
    return fmaf(LAM, fmaxf(x, 0.f), fmaf(ALA, e, -ALA));
}

__device__ __forceinline__ float bfbits2f(unsigned short u) {
    return __uint_as_float(((unsigned)u) << 16);
}

__device__ __forceinline__ unsigned short f2bfbits(float f) {
    union { __hip_bfloat16 h; unsigned short u; } cv;
    cv.h = __float2bfloat16(f);
    return cv.u;
}

__device__ __forceinline__ float ldf(const void* p, int i, int isbf) {
    return isbf ? bfbits2f(((const unsigned short*)p)[i]) : ((const float*)p)[i];
}

// ---- dtype detection ------------------------------------------------------
__global__ void k_detect(const unsigned int* __restrict__ xw,
                         const unsigned int* __restrict__ cw,
                         const unsigned int* __restrict__ ew,
                         int* __restrict__ flags) {
    if (threadIdx.x != 0 || blockIdx.x != 0) return;
    int nb = 0;
    for (int i = 0; i < 64; ++i) {
        unsigned lo = xw[i] & 0xffffu;
        unsigned e = (lo >> 7) & 0xff;
        if (e >= 112 && e <= 134) ++nb;
    }
    flags[0] = (nb >= 32) ? 1 : 0;
    int cz = 0, ez = 0;
    for (int i = 0; i < 64; ++i) {
        if (cw[2 * i + 1] == 0u) ++cz;
        if (ew[2 * i + 1] == 0u) ++ez;
    }
    flags[1] = (cz >= 48) ? 1 : 0;
    flags[2] = (ez >= 48) ? 1 : 0;
}

__device__ __forceinline__ void ld_edge(const void* edges, long long e, int e64,
                                        int& s, int& d) {
    if (e64) {
        const long long* el = (const long long*)edges;
        s = (int)el[e];
        d = (int)el[NE + e];
    } else {
        const int* ei = (const int*)edges;
        s = ei[e];
        d = ei[NE + e];
    }
}

// ---- Binning pass 1: edges -> 61 super-buckets. SINGLE global read:
//      entries staged in LDS during the histogram pass. Runs ~67 entries
//      (268 B) at 61 buckets -> still fully coalesced writes. --------------
__global__ __launch_bounds__(256) void k_bin1(const void* __restrict__ edges,
        int* __restrict__ scur, unsigned int* __restrict__ slist,
        const int* __restrict__ flags) {
    __shared__ unsigned int tmp[B1CH];         // 16 KB  (s<<11)|dlocal
    __shared__ unsigned char tsup[B1CH];       // 4 KB
    __shared__ unsigned int ord[B1CH];         // 16 KB
    __shared__ unsigned char osup[B1CH];       // 4 KB
    __shared__ int hist[64];
    __shared__ int lstart[64];
    __shared__ int ofs[64];
    __shared__ int gbase[64];                  // ~41 KB -> 3 blocks/CU

    int tid = threadIdx.x;
    long long base = (long long)blockIdx.x * B1CH;
    int chunk = (int)(NE - base);
    if (chunk > B1CH) chunk = B1CH;
    int e64 = flags[2];

    if (tid < 64) hist[tid] = 0;
    __syncthreads();

    // phase A: single global read -> LDS stage + histogram
    for (int i = 0; i < B1CH / 256; ++i) {
        int idx = i * 256 + tid;
        if (idx < chunk) {
            int s, d;
            ld_edge(edges, base + idx, e64, s, d);
            int sup = d / SSPAN;
            tmp[idx] = ((unsigned)s << 11) | (unsigned)(d - sup * SSPAN);
            tsup[idx] = (unsigned char)sup;
            atomicAdd(&hist[sup], 1);
        }
    }
    __syncthreads();

    // phase B: serial scan (61) + global reservation
    if (tid == 0) {
        int run = 0;
        for (int b = 0; b < NSUP; ++b) {
            lstart[b] = run;
            run += hist[b];
        }
    }
    __syncthreads();
    if (tid < NSUP) {
        int c = hist[tid];
        int g = 0;
        if (c > 0) g = atomicAdd(&scur[tid], c);
        gbase[tid] = g;
        ofs[tid] = lstart[tid];
    }
    __syncthreads();

    // phase C: reorder within LDS
    for (int i = 0; i < B1CH / 256; ++i) {
        int idx = i * 256 + tid;
        if (idx < chunk) {
            int sup = tsup[idx];
            int pos = atomicAdd(&ofs[sup], 1);
            ord[pos] = tmp[idx];
            osup[pos] = (unsigned char)sup;
        }
    }
    __syncthreads();

    // phase D: coalesced write-out
    for (int i = 0; i < B1CH / 256; ++i) {
        int idx = i * 256 + tid;
        if (idx < chunk) {
            int sup = osup[idx];
            int p = gbase[sup] + (idx - lstart[sup]);
            if (p < SCAP) slist[(long long)sup * SCAP + p] = ord[idx];
        }
    }
}

#define SCH2 ((SCAP + B2CH - 1) / B2CH)   // 14 chunks per super

// ---- Binning pass 2: super -> 13 fine buckets. SINGLE slist read. --------
__global__ __launch_bounds__(256) void k_bin2(const int* __restrict__ scur,
        const unsigned int* __restrict__ slist,
        int* __restrict__ gcur, unsigned int* __restrict__ glist) {
    __shared__ unsigned int tmp[B2CH];         // 16 KB
    __shared__ unsigned int ord[B2CH];         // 16 KB
    __shared__ unsigned char ofid[B2CH];       // 4 KB
    __shared__ int hist[16];
    __shared__ int lstart[16];
    __shared__ int ofs[16];
    __shared__ int gbase[16];                  // ~36.5 KB -> 4 blocks/CU

    int tid = threadIdx.x;
    int sup = blockIdx.x / SCH2;
    int ch = blockIdx.x % SCH2;
    int scnt = scur[sup];
    if (scnt > SCAP) scnt = SCAP;
    int start = ch * B2CH;
    int cnt = scnt - start;
    if (cnt <= 0) return;
    if (cnt > B2CH) cnt = B2CH;
    const unsigned int* sp = slist + (long long)sup * SCAP + start;

    if (tid < 16) hist[tid] = 0;
    __syncthreads();

    // phase A: single global read -> LDS stage + histogram
    for (int i = 0; i < B2CH / 256; ++i) {
        int idx = i * 256 + tid;
        if (idx < cnt) {
            unsigned u = sp[idx];
            tmp[idx] = u;
            atomicAdd(&hist[(u & 2047) >> 7], 1);
        }
    }
    __syncthreads();

    if (tid == 0) {
        int run = 0;
        for (int b = 0; b < SFB; ++b) {
            lstart[b] = run;
            run += hist[b];
        }
    }
    __syncthreads();
    if (tid < SFB) {
        int c = hist[tid];
        int g = 0;
        int bf = sup * SFB + tid;
        if (c > 0 && bf < NBK) g = atomicAdd(&gcur[bf], c);
        gbase[tid] = g;
        ofs[tid] = lstart[tid];
    }
    __syncthreads();

    // phase C: reorder within LDS (convert to (s<<7)|dl127)
    for (int i = 0; i < B2CH / 256; ++i) {
        int idx = i * 256 + tid;
        if (idx < cnt) {
            unsigned u = tmp[idx];
            int dl = u & 2047;
            int f = dl >> 7;
            int pos = atomicAdd(&ofs[f], 1);
            ord[pos] = ((u >> 11) << 7) | (unsigned)(dl & 127);
            ofid[pos] = (unsigned char)f;
        }
    }
    __syncthreads();

    // phase D: coalesced write-out (runs ~315 entries)
    for (int i = 0; i < B2CH / 256; ++i) {
        int idx = i * 256 + tid;
        if (idx < cnt) {
            int f = ofid[idx];
            int bf = sup * SFB + f;
            int p = gbase[f] + (idx - lstart[f]);
            if (p < CAP) glist[(long long)bf * CAP + p] = ord[idx];
        }
    }
}

// ---- Counting-sort each bucket by dl. SINGLE glist read (LDS-staged),
//      in-place write-back; emits per-dst CSR. -----------------------------
__global__ __launch_bounds__(256) void k_sort(const int* __restrict__ gcur,
        unsigned int* __restrict__ glist,
        int* __restrict__ dstoff, int* __restrict__ ddeg) {
    __shared__ unsigned int tmp[CAP];      // 20 KB
    __shared__ unsigned int sorted[CAP];   // 20 KB
    __shared__ int hist[BSZ];
    __shared__ int incl[BSZ];
    __shared__ int cur[BSZ];               // ~41.5 KB -> 3 blocks/CU
    int b = blockIdx.x;
    int tid = threadIdx.x;
    int cnt = gcur[b];
    if (cnt > CAP) cnt = CAP;
    unsigned int* lp = glist + (long long)b * CAP;

    if (tid < BSZ) hist[tid] = 0;
    __syncthreads();
    // single global read -> LDS + histogram
    for (int k = tid; k < cnt; k += 256) {
        unsigned u = lp[k];
        tmp[k] = u;
        atomicAdd(&hist[u & 127], 1);
    }
    __syncthreads();
    if (tid < BSZ) incl[tid] = hist[tid];
    __syncthreads();
    for (int off = 1; off < BSZ; off <<= 1) {
        int v = (tid < BSZ && tid >= off) ? incl[tid - off] : 0;
        __syncthreads();
        if (tid < BSZ && tid >= off) incl[tid] += v;
        __syncthreads();
    }
    if (tid < BSZ) {
        int excl = incl[tid] - hist[tid];
        cur[tid] = excl;
        int d = b * BSZ + tid;
        if (d < NG) {
            dstoff[d] = b * CAP + excl;
            ddeg[d] = hist[tid];
        }
    }
    __syncthreads();
    for (int k = tid; k < cnt; k += 256) {
        unsigned u = tmp[k];
        int pos = atomicAdd(&cur[u & 127], 1);
        sorted[pos] = u >> 7;
    }
    __syncthreads();
    for (int k = tid; k < cnt; k += 256) lp[k] = sorted[k];
}

// ---- Gather+Node 1 fused: 16 threads/dst, paired independent gathers ------
__global__ __launch_bounds__(256) void k_gather1(const int* __restrict__ dstoff,
        const int* __restrict__ ddeg, const unsigned int* __restrict__ glist,
        const void* __restrict__ xg,
        const void* __restrict__ W1r, const void* __restrict__ W1o,
        const void* __restrict__ b1, unsigned short* __restrict__ hbf,
        const int* __restrict__ flags) {
    int gid = blockIdx.x * 256 + threadIdx.x;
    int d = gid >> 4;
    if (d >= NG) return;
    int q = gid & 15;
    int isbf = flags[0];
    int start = dstoff[d];
    int deg = ddeg[d];
    float a0 = 0.f, a1 = 0.f, a2 = 0.f, a3 = 0.f;
    int k = q;
    for (; k + 16 < deg; k += 32) {
        int s0 = glist[start + k];
        int s1 = glist[start + k + 16];
        if (isbf) {
            ushort4 r0 = *(const ushort4*)((const unsigned short*)xg + s0 * 4);
            ushort4 r1 = *(const ushort4*)((const unsigned short*)xg + s1 * 4);
            a0 += bfbits2f(r0.x) + bfbits2f(r1.x);
            a1 += bfbits2f(r0.y) + bfbits2f(r1.y);
            a2 += bfbits2f(r0.z) + bfbits2f(r1.z);
            a3 += bfbits2f(r0.w) + bfbits2f(r1.w);
        } else {
            float4 r0 = *(const float4*)((const float*)xg + s0 * 4);
            float4 r1 = *(const float4*)((const float*)xg + s1 * 4);
            a0 += r0.x + r1.x;
            a1 += r0.y + r1.y;
            a2 += r0.z + r1.z;
            a3 += r0.w + r1.w;
        }
    }
    for (; k < deg; k += 16) {
        int s = glist[start + k];
        if (isbf) {
            ushort4 r = *(const ushort4*)((const unsigned short*)xg + s * 4);
            a0 += bfbits2f(r.x); a1 += bfbits2f(r.y);
            a2 += bfbits2f(r.z); a3 += bfbits2f(r.w);
        } else {
            float4 r = *(const float4*)((const float*)xg + s * 4);
            a0 += r.x; a1 += r.y; a2 += r.z; a3 += r.w;
        }
    }
#pragma unroll
    for (int off = 1; off < 16; off <<= 1) {
        a0 += __shfl_xor(a0, off);
        a1 += __shfl_xor(a1, off);
        a2 += __shfl_xor(a2, off);
        a3 += __shfl_xor(a3, off);
    }
    if (q < 8) {
        float a[4] = {a0, a1, a2, a3};
        float v = ldf(b1, q, isbf);
#pragma unroll
        for (int c = 0; c < 4; ++c)
            v += a[c] * ldf(W1r, c * 8 + q, isbf)
               + ldf(xg, d * 4 + c, isbf) * ldf(W1o, c * 8 + q, isbf);
        hbf[d * 8 + q] = f2bfbits(selu_f(v));
    }
}

// ---- Gather+Node 2 fused: 16 threads/dst; lane q -> output j=q ------------
__global__ __launch_bounds__(256) void k_gather2(const int* __restrict__ dstoff,
        const int* __restrict__ ddeg, const unsigned int* __restrict__ glist,
        const ushortx8* __restrict__ hbf,
        const void* __restrict__ W2r, const void* __restrict__ W2o,
        const void* __restrict__ b2, unsigned short* __restrict__ xs,
        const int* __restrict__ flags) {
    int gid = blockIdx.x * 256 + threadIdx.x;
    int d = gid >> 4;
    if (d >= NG) return;
    int q = gid & 15;
    int isbf = flags[0];
    int start = dstoff[d];
    int deg = ddeg[d];
    float a[8] = {0.f, 0.f, 0.f, 0.f, 0.f, 0.f, 0.f, 0.f};
    int k = q;
    for (; k + 16 < deg; k += 32) {
        int s0 = glist[start + k];
        int s1 = glist[start + k + 16];
        ushortx8 r0 = hbf[s0];
        ushortx8 r1 = hbf[s1];
#pragma unroll
        for (int c = 0; c < 8; ++c)
            a[c] += bfbits2f((unsigned short)r0[c]) + bfbits2f((unsigned short)r1[c]);
    }
    for (; k < deg; k += 16) {
        int s = glist[start + k];
        ushortx8 r = hbf[s];
#pragma unroll
        for (int c = 0; c < 8; ++c) a[c] += bfbits2f((unsigned short)r[c]);
    }
#pragma unroll
    for (int off = 1; off < 16; off <<= 1) {
#pragma unroll
        for (int c = 0; c < 8; ++c) a[c] += __shfl_xor(a[c], off);
    }
    ushortx8 hr = hbf[d];
    float hv[8];
#pragma unroll
    for (int c = 0; c < 8; ++c) hv[c] = bfbits2f((unsigned short)hr[c]);
    float v = ldf(b2, q, isbf);
#pragma unroll
    for (int c = 0; c < 8; ++c)
        v += a[c] * ldf(W2r, c * 16 + q, isbf)
           + hv[c] * ldf(W2o, c * 16 + q, isbf);
    xs[d * 16 + q] = f2bfbits(selu_f(v));
}

// ---- fc_unconnected -> x_stacked[NG:NG+NU] (bf16), NO selu ----------------
__global__ __launch_bounds__(256) void k_unconn(const void* __restrict__ xu,
        const void* __restrict__ Wun, const void* __restrict__ bun,
        unsigned short* __restrict__ xs, const int* __restrict__ flags) {
    int u = blockIdx.x * 256 + threadIdx.x;
    if (u >= NU) return;
    int isbf = flags[0];
    float x[4];
#pragma unroll
    for (int k = 0; k < 4; ++k) x[k] = ldf(xu, u * 4 + k, isbf);
    ushortx8 lo, hi;
#pragma unroll
    for (int j = 0; j < 16; ++j) {
        float v = ldf(bun, j, isbf);
#pragma unroll
        for (int k = 0; k < 4; ++k)
            v += x[k] * ldf(Wun, k * 16 + j, isbf);
        unsigned short bb = f2bfbits(v);
        if (j < 8) lo[j] = bb; else hi[j - 8] = bb;
    }
    ushortx8* xp = (ushortx8*)(xs + (NG + u) * 16);
    xp[0] = lo;
    xp[1] = hi;
}

__device__ __forceinline__ int2 ld_cand2(const void* cand, int c, int c64) {
    if (c64) {
        const long long* cl = (const long long*)cand;
        return make_int2((int)cl[2 * c], (int)cl[2 * c + 1]);
    }
    return *(const int2*)((const int*)cand + 2 * c);
}

// ---- FC head: persistent waves, 2-deep software-pipelined gather.
//      TRANSPOSED MFMA with L2E pre-folded: wfrag/cbias scaled by L2E so the
//      MFMA emits ac = L2E*v directly. Epilogue per hidden unit (4 VALU + 1
//      trans, single 16-reg constant array):
//        contrib = w2s * ( max(ac,0) + AR2 * exp2(min(ac,0)) )
//      where w2s = w2*LAM/L2E, AR2 = ALPHA*L2E (scalar). Constant term
//      -sum(w2*ALA) folded into c_corr. __launch_bounds__(256,5): VGPR cap
//      102 keeps wfrag+cbias+w2s+pipeline fully resident (VGPR=60 at 8
//      waves forced per-tile remat of constants: +~180 VALU/tile, +4MB
//      FETCH re-reads -- R2 counters).
__global__ __launch_bounds__(256, 5) void k_fc(const unsigned short* __restrict__ xs,
        const void* __restrict__ cand,
        const void* __restrict__ Wfc1, const void* __restrict__ bfc1,
        const void* __restrict__ Wfc2, const void* __restrict__ bfc2,
        void* __restrict__ out, const int* __restrict__ flags) {
    const float LAM = 1.0507009873554805f;
    const float ALA = 1.7580993408473766f;  // LAM * ALPHA
    const float L2E = 1.44269504088896340736f;
    const float AR2 = 1.6732632423543772f * 1.44269504088896340736f;  // ALPHA*L2E
    const float SCL = 1.0507009873554805f / 1.44269504088896340736f;  // LAM/L2E
    int lane = threadIdx.x & 63;
    int wid = (blockIdx.x * blockDim.x + threadIdx.x) >> 6;
    int m = lane & 15;
    int half = lane >> 4;
    int isbf = flags[0], c64 = flags[1];

    short8 wfrag[4];
    floatx4 cbias[4];
    float w2s[4][4];
    float c_corr;
    if (isbf) {
        const unsigned short* W1p = (const unsigned short*)Wfc1;
#pragma unroll
        for (int t = 0; t < 4; ++t)
#pragma unroll
            for (int j = 0; j < 8; ++j)
                wfrag[t][j] = (short)f2bfbits(
                    bfbits2f(W1p[(half * 8 + j) * 64 + t * 16 + m]) * L2E);
        const unsigned short* b1p = (const unsigned short*)bfc1;
        const unsigned short* w2p = (const unsigned short*)Wfc2;
        float asum = 0.f;
#pragma unroll
        for (int t = 0; t < 4; ++t)
#pragma unroll
            for (int r = 0; r < 4; ++r) {
                int h = t * 16 + half * 4 + r;
                cbias[t][r] = bfbits2f(b1p[h]) * L2E;
                float w2 = bfbits2f(w2p[h]);
                w2s[t][r] = w2 * SCL;
                asum += w2 * ALA;
            }
        asum += __shfl_xor(asum, 16, 64);
        asum += __shfl_xor(asum, 32, 64);
        c_corr = bfbits2f(((const unsigned short*)bfc2)[0]) - asum;
    } else {
        const float* W1p = (const float*)Wfc1;
#pragma unroll
        for (int t = 0; t < 4; ++t)
#pragma unroll
            for (int j = 0; j < 8; ++j)
                wfrag[t][j] = (short)f2bfbits(
                    W1p[(half * 8 + j) * 64 + t * 16 + m] * L2E);
        const float* b1p = (const float*)bfc1;
        const float* w2p = (const float*)Wfc2;
        float asum = 0.f;
#pragma unroll
        for (int t = 0; t < 4; ++t)
#pragma unroll
            for (int r = 0; r < 4; ++r) {
                int h = t * 16 + half * 4 + r;
                cbias[t][r] = b1p[h] * L2E;
                float w2 = w2p[h];
                w2s[t][r] = w2 * SCL;
                asum += w2 * ALA;
            }
        asum += __shfl_xor(asum, 16, 64);
        asum += __shfl_xor(asum, 32, 64);
        c_corr = ((const float*)bfc2)[0] - asum;
    }

    const int nTiles = NC / 16;
    int nW = (gridDim.x * blockDim.x) >> 6;
    if (wid >= nTiles) return;

    // 2-deep gather pipeline: af for tiles t, t+nW in flight; cand 3 ahead.
    int t1 = wid + nW, t2 = wid + 2 * nW;
    int2 cc0 = ld_cand2(cand, wid * 16 + m, c64);
    int2 cc1 = ld_cand2(cand, ((t1 < nTiles) ? t1 : wid) * 16 + m, c64);
    int2 cc2 = ld_cand2(cand, ((t2 < nTiles) ? t2 : wid) * 16 + m, c64);
    int half1 = half & 1;
    {
        int row0 = (half < 2) ? cc0.x : cc0.y;
        short8 af0 = *(const short8*)(xs + row0 * 16 + half1 * 8);
        int row1 = (half < 2) ? cc1.x : cc1.y;
        short8 af1 = *(const short8*)(xs + row1 * 16 + half1 * 8);

#pragma unroll 2
        for (int t = wid; t < nTiles; t += nW) {
            int tn3 = t + 3 * nW;
            int2 cc3 = ld_cand2(cand, ((tn3 < nTiles) ? tn3 : t) * 16 + m, c64);
            int row2 = (half < 2) ? cc2.x : cc2.y;
            short8 af2 = *(const short8*)(xs + row2 * 16 + half1 * 8);

            float part = 0.f;
#pragma unroll
            for (int tt = 0; tt < 4; ++tt) {
                floatx4 ac = __builtin_amdgcn_mfma_f32_16x16x32_bf16(
                    wfrag[tt], af0, cbias[tt], 0, 0, 0);
#pragma unroll
                for (int r = 0; r < 4; ++r) {
                    float v = ac[r];
                    float mx = fmaxf(v, 0.f);
                    float e = __builtin_amdgcn_exp2f(fminf(v, 0.f));
                    part = fmaf(w2s[tt][r], fmaf(AR2, e, mx), part);
                }
            }
            part += __shfl_xor(part, 16, 64);
            part += __shfl_xor(part, 32, 64);
            if (half == 0) {
                float o = part + c_corr;
                if (isbf) ((unsigned short*)out)[t * 16 + m] = f2bfbits(o);
                else ((float*)out)[t * 16 + m] = o;
            }
            af0 = af1;
            af1 = af2;
            cc2 = cc3;
        }
    }
}

extern "C" void kernel_launch(void* const* d_in, const int* in_sizes, int n_in,
                              void* d_out, int out_size, void* d_ws, size_t ws_size,
                              hipStream_t stream) {
    const void* x_u = d_in[0];
    const void* x_g = d_in[1];
    const void* cand = d_in[2];
    const void* edges = d_in[3];
    const void* W1r = d_in[4];
    const void* W1o = d_in[5];
    const void* b1 = d_in[6];
    const void* W2r = d_in[7];
    const void* W2o = d_in[8];
    const void* b2 = d_in[9];
    const void* Wun = d_in[10];
    const void* bun = d_in[11];
    const void* Wfc1 = d_in[12];
    const void* bfc1 = d_in[13];
    const void* Wfc2 = d_in[14];
    const void* bfc2 = d_in[15];

    char* ws = (char*)d_ws;
    int* flags = (int*)ws;                                  // 64 B
    int* gcur = (int*)(ws + 64);                            // 782*4 -> 3200 B
    int* scur = (int*)(ws + 3264);                          // 61*4  -> 244 B
    unsigned int* glist = (unsigned int*)(ws + 4160);       // 16.01 MB
    size_t glist_bytes = (size_t)NBK * CAP * 4;             // 16010240
    char* p = ws + 4160 + glist_bytes;
    // slist (13.75 MB) overlaps the post-binning buffers: dead after k_bin2.
    unsigned int* slist = (unsigned int*)p;                 // 61*56320*4 = 13.74 MB
    int* dstoff = (int*)p;                                  // 400 KB
    int* ddeg = (int*)(p + 400000);                         // 400 KB
    unsigned short* hbf = (unsigned short*)(p + 800000);    // 1.6 MB
    unsigned short* xs = (unsigned short*)(p + 2400000);    // 6.4 MB

    hipMemsetAsync(gcur, 0, 3456, stream);   // zeroes gcur + scur

    k_detect<<<1, 64, 0, stream>>>((const unsigned int*)x_u,
                                   (const unsigned int*)cand,
                                   (const unsigned int*)edges, flags);
    k_bin1<<<(NE + B1CH - 1) / B1CH, 256, 0, stream>>>(edges, scur, slist, flags);
    k_bin2<<<NSUP * SCH2, 256, 0, stream>>>(scur, slist, gcur, glist);
    k_sort<<<NBK, 256, 0, stream>>>(gcur, glist, dstoff, ddeg);
    k_gather1<<<(16 * NG + 255) / 256, 256, 0, stream>>>(dstoff, ddeg, glist, x_g,
                                                         W1r, W1o, b1, hbf, flags);
    k_gather2<<<(16 * NG + 255) / 256, 256, 0, stream>>>(dstoff, ddeg, glist,
                                                         (const ushortx8*)hbf,
                                                         W2r, W2o, b2, xs, flags);
    k_unconn<<<(NU + 255) / 256, 256, 0, stream>>>(x_u, Wun, bun, xs, flags);
    k_fc<<<2048, 256, 0, stream>>>(xs, cand, Wfc1, bfc1, Wfc2, bfc2, d_out, flags);
}

// Round 4
// 272.306 us; speedup vs baseline: 1.0307x; 1.0024x over previous
//
#include <hip/hip_runtime.h>
#include <hip/hip_bf16.h>

#define NG 100000
#define NU 100000
#define NE 3200000
#define NC 2000000

// dst-bucket binning: 128 dsts per bucket
#define BSZ 128
#define NBK 782          // ceil(NG/BSZ)
#define CAP 5120         // entries per fine bucket (mean 4096, +16 sigma)

// two-level binning: 61 super-buckets of 13 fine buckets (61*13=793>=782)
#define NSUP 61
#define SFB 13
#define SSPAN (SFB * BSZ)   // 1664 dsts per super
#define SCAP 56320          // entries per super (mean 52459, +17 sigma)
#define B1CH 4096           // edges per bin1 block (LDS-staged single read)
#define B2CH 4096           // entries per bin2 block

typedef __attribute__((ext_vector_type(8))) short short8;
typedef __attribute__((ext_vector_type(4))) float floatx4;
typedef unsigned short ushortx8 __attribute__((ext_vector_type(8)));

// branchless SELU on the HW transcendental (6 VALU ops)
__device__ __forceinline__ float selu_f(float x) {
    const float LAM = 1.0507009873554805f;
    const float ALA = 1.7580993408473766f;  // LAM * ALPHA
    const float L2E = 1.44269504088896340736f;
    float e = __builtin_amdgcn_exp2f(fminf(x, 0.f) * L2E);
    return fmaf(LAM, fmaxf(x, 0.f), fmaf(ALA, e, -ALA));
}

__device__ __forceinline__ float bfbits2f(unsigned short u) {
    return __uint_as_float(((unsigned)u) << 16);
}

__device__ __forceinline__ unsigned short f2bfbits(float f) {
    union { __hip_bfloat16 h; unsigned short u; } cv;
    cv.h = __float2bfloat16(f);
    return cv.u;
}

__device__ __forceinline__ float ldf(const void* p, int i, int isbf) {
    return isbf ? bfbits2f(((const unsigned short*)p)[i]) : ((const float*)p)[i];
}

// ---- dtype detection ------------------------------------------------------
__global__ void k_detect(const unsigned int* __restrict__ xw,
                         const unsigned int* __restrict__ cw,
                         const unsigned int* __restrict__ ew,
                         int* __restrict__ flags) {
    if (threadIdx.x != 0 || blockIdx.x != 0) return;
    int nb = 0;
    for (int i = 0; i < 64; ++i) {
        unsigned lo = xw[i] & 0xffffu;
        unsigned e = (lo >> 7) & 0xff;
        if (e >= 112 && e <= 134) ++nb;
    }
    flags[0] = (nb >= 32) ? 1 : 0;
    int cz = 0, ez = 0;
    for (int i = 0; i < 64; ++i) {
        if (cw[2 * i + 1] == 0u) ++cz;
        if (ew[2 * i + 1] == 0u) ++ez;
    }
    flags[1] = (cz >= 48) ? 1 : 0;
    flags[2] = (ez >= 48) ? 1 : 0;
}

__device__ __forceinline__ void ld_edge(const void* edges, long long e, int e64,
                                        int& s, int& d) {
    if (e64) {
        const long long* el = (const long long*)edges;
        s = (int)el[e];
        d = (int)el[NE + e];
    } else {
        const int* ei = (const int*)edges;
        s = ei[e];
        d = ei[NE + e];
    }
}

// ---- Binning pass 1: edges -> 61 super-buckets. SINGLE global read:
//      entries staged in LDS during the histogram pass. Runs ~67 entries
//      (268 B) at 61 buckets -> still fully coalesced writes. --------------
__global__ __launch_bounds__(256) void k_bin1(const void* __restrict__ edges,
        int* __restrict__ scur, unsigned int* __restrict__ slist,
        const int* __restrict__ flags) {
    __shared__ unsigned int tmp[B1CH];         // 16 KB  (s<<11)|dlocal
    __shared__ unsigned char tsup[B1CH];       // 4 KB
    __shared__ unsigned int ord[B1CH];         // 16 KB
    __shared__ unsigned char osup[B1CH];       // 4 KB
    __shared__ int hist[64];
    __shared__ int lstart[64];
    __shared__ int ofs[64];
    __shared__ int gbase[64];                  // ~41 KB -> 3 blocks/CU

    int tid = threadIdx.x;
    long long base = (long long)blockIdx.x * B1CH;
    int chunk = (int)(NE - base);
    if (chunk > B1CH) chunk = B1CH;
    int e64 = flags[2];

    if (tid < 64) hist[tid] = 0;
    __syncthreads();

    // phase A: single global read -> LDS stage + histogram
    for (int i = 0; i < B1CH / 256; ++i) {
        int idx = i * 256 + tid;
        if (idx < chunk) {
            int s, d;
            ld_edge(edges, base + idx, e64, s, d);
            int sup = d / SSPAN;
            tmp[idx] = ((unsigned)s << 11) | (unsigned)(d - sup * SSPAN);
            tsup[idx] = (unsigned char)sup;
            atomicAdd(&hist[sup], 1);
        }
    }
    __syncthreads();

    // phase B: serial scan (61) + global reservation
    if (tid == 0) {
        int run = 0;
        for (int b = 0; b < NSUP; ++b) {
            lstart[b] = run;
            run += hist[b];
        }
    }
    __syncthreads();
    if (tid < NSUP) {
        int c = hist[tid];
        int g = 0;
        if (c > 0) g = atomicAdd(&scur[tid], c);
        gbase[tid] = g;
        ofs[tid] = lstart[tid];
    }
    __syncthreads();

    // phase C: reorder within LDS
    for (int i = 0; i < B1CH / 256; ++i) {
        int idx = i * 256 + tid;
        if (idx < chunk) {
            int sup = tsup[idx];
            int pos = atomicAdd(&ofs[sup], 1);
            ord[pos] = tmp[idx];
            osup[pos] = (unsigned char)sup;
        }
    }
    __syncthreads();

    // phase D: coalesced write-out
    for (int i = 0; i < B1CH / 256; ++i) {
        int idx = i * 256 + tid;
        if (idx < chunk) {
            int sup = osup[idx];
            int p = gbase[sup] + (idx - lstart[sup]);
            if (p < SCAP) slist[(long long)sup * SCAP + p] = ord[idx];
        }
    }
}

#define SCH2 ((SCAP + B2CH - 1) / B2CH)   // 14 chunks per super

// ---- Binning pass 2: super -> 13 fine buckets. SINGLE slist read. --------
__global__ __launch_bounds__(256) void k_bin2(const int* __restrict__ scur,
        const unsigned int* __restrict__ slist,
        int* __restrict__ gcur, unsigned int* __restrict__ glist) {
    __shared__ unsigned int tmp[B2CH];         // 16 KB
    __shared__ unsigned int ord[B2CH];         // 16 KB
    __shared__ unsigned char ofid[B2CH];       // 4 KB
    __shared__ int hist[16];
    __shared__ int lstart[16];
    __shared__ int ofs[16];
    __shared__ int gbase[16];                  // ~36.5 KB -> 4 blocks/CU

    int tid = threadIdx.x;
    int sup = blockIdx.x / SCH2;
    int ch = blockIdx.x % SCH2;
    int scnt = scur[sup];
    if (scnt > SCAP) scnt = SCAP;
    int start = ch * B2CH;
    int cnt = scnt - start;
    if (cnt <= 0) return;
    if (cnt > B2CH) cnt = B2CH;
    const unsigned int* sp = slist + (long long)sup * SCAP + start;

    if (tid < 16) hist[tid] = 0;
    __syncthreads();

    // phase A: single global read -> LDS stage + histogram
    for (int i = 0; i < B2CH / 256; ++i) {
        int idx = i * 256 + tid;
        if (idx < cnt) {
            unsigned u = sp[idx];
            tmp[idx] = u;
            atomicAdd(&hist[(u & 2047) >> 7], 1);
        }
    }
    __syncthreads();

    if (tid == 0) {
        int run = 0;
        for (int b = 0; b < SFB; ++b) {
            lstart[b] = run;
            run += hist[b];
        }
    }
    __syncthreads();
    if (tid < SFB) {
        int c = hist[tid];
        int g = 0;
        int bf = sup * SFB + tid;
        if (c > 0 && bf < NBK) g = atomicAdd(&gcur[bf], c);
        gbase[tid] = g;
        ofs[tid] = lstart[tid];
    }
    __syncthreads();

    // phase C: reorder within LDS (convert to (s<<7)|dl127)
    for (int i = 0; i < B2CH / 256; ++i) {
        int idx = i * 256 + tid;
        if (idx < cnt) {
            unsigned u = tmp[idx];
            int dl = u & 2047;
            int f = dl >> 7;
            int pos = atomicAdd(&ofs[f], 1);
            ord[pos] = ((u >> 11) << 7) | (unsigned)(dl & 127);
            ofid[pos] = (unsigned char)f;
        }
    }
    __syncthreads();

    // phase D: coalesced write-out (runs ~315 entries)
    for (int i = 0; i < B2CH / 256; ++i) {
        int idx = i * 256 + tid;
        if (idx < cnt) {
            int f = ofid[idx];
            int bf = sup * SFB + f;
            int p = gbase[f] + (idx - lstart[f]);
            if (p < CAP) glist[(long long)bf * CAP + p] = ord[idx];
        }
    }
}

// ---- Counting-sort each bucket by dl. SINGLE glist read (LDS-staged),
//      in-place write-back; emits per-dst CSR. -----------------------------
__global__ __launch_bounds__(256) void k_sort(const int* __restrict__ gcur,
        unsigned int* __restrict__ glist,
        int* __restrict__ dstoff, int* __restrict__ ddeg) {
    __shared__ unsigned int tmp[CAP];      // 20 KB
    __shared__ unsigned int sorted[CAP];   // 20 KB
    __shared__ int hist[BSZ];
    __shared__ int incl[BSZ];
    __shared__ int cur[BSZ];               // ~41.5 KB -> 3 blocks/CU
    int b = blockIdx.x;
    int tid = threadIdx.x;
    int cnt = gcur[b];
    if (cnt > CAP) cnt = CAP;
    unsigned int* lp = glist + (long long)b * CAP;

    if (tid < BSZ) hist[tid] = 0;
    __syncthreads();
    // single global read -> LDS + histogram
    for (int k = tid; k < cnt; k += 256) {
        unsigned u = lp[k];
        tmp[k] = u;
        atomicAdd(&hist[u & 127], 1);
    }
    __syncthreads();
    if (tid < BSZ) incl[tid] = hist[tid];
    __syncthreads();
    for (int off = 1; off < BSZ; off <<= 1) {
        int v = (tid < BSZ && tid >= off) ? incl[tid - off] : 0;
        __syncthreads();
        if (tid < BSZ && tid >= off) incl[tid] += v;
        __syncthreads();
    }
    if (tid < BSZ) {
        int excl = incl[tid] - hist[tid];
        cur[tid] = excl;
        int d = b * BSZ + tid;
        if (d < NG) {
            dstoff[d] = b * CAP + excl;
            ddeg[d] = hist[tid];
        }
    }
    __syncthreads();
    for (int k = tid; k < cnt; k += 256) {
        unsigned u = tmp[k];
        int pos = atomicAdd(&cur[u & 127], 1);
        sorted[pos] = u >> 7;
    }
    __syncthreads();
    for (int k = tid; k < cnt; k += 256) lp[k] = sorted[k];
}

// ---- Gather+Node 1 fused: 16 threads/dst, paired independent gathers.
//      isbf hoisted out of the edge loop (wave-uniform). -------------------
__global__ __launch_bounds__(256) void k_gather1(const int* __restrict__ dstoff,
        const int* __restrict__ ddeg, const unsigned int* __restrict__ glist,
        const void* __restrict__ xg,
        const void* __restrict__ W1r, const void* __restrict__ W1o,
        const void* __restrict__ b1, unsigned short* __restrict__ hbf,
        const int* __restrict__ flags) {
    int gid = blockIdx.x * 256 + threadIdx.x;
    int d = gid >> 4;
    if (d >= NG) return;
    int q = gid & 15;
    int isbf = flags[0];
    int start = dstoff[d];
    int deg = ddeg[d];
    float a0 = 0.f, a1 = 0.f, a2 = 0.f, a3 = 0.f;
    if (isbf) {
        const unsigned short* xp = (const unsigned short*)xg;
        int k = q;
        for (; k + 16 < deg; k += 32) {
            int s0 = glist[start + k];
            int s1 = glist[start + k + 16];
            ushort4 r0 = *(const ushort4*)(xp + s0 * 4);
            ushort4 r1 = *(const ushort4*)(xp + s1 * 4);
            a0 += bfbits2f(r0.x) + bfbits2f(r1.x);
            a1 += bfbits2f(r0.y) + bfbits2f(r1.y);
            a2 += bfbits2f(r0.z) + bfbits2f(r1.z);
            a3 += bfbits2f(r0.w) + bfbits2f(r1.w);
        }
        for (; k < deg; k += 16) {
            int s = glist[start + k];
            ushort4 r = *(const ushort4*)(xp + s * 4);
            a0 += bfbits2f(r.x); a1 += bfbits2f(r.y);
            a2 += bfbits2f(r.z); a3 += bfbits2f(r.w);
        }
    } else {
        const float* xp = (const float*)xg;
        int k = q;
        for (; k + 16 < deg; k += 32) {
            int s0 = glist[start + k];
            int s1 = glist[start + k + 16];
            float4 r0 = *(const float4*)(xp + s0 * 4);
            float4 r1 = *(const float4*)(xp + s1 * 4);
            a0 += r0.x + r1.x;
            a1 += r0.y + r1.y;
            a2 += r0.z + r1.z;
            a3 += r0.w + r1.w;
        }
        for (; k < deg; k += 16) {
            int s = glist[start + k];
            float4 r = *(const float4*)(xp + s * 4);
            a0 += r.x; a1 += r.y; a2 += r.z; a3 += r.w;
        }
    }
#pragma unroll
    for (int off = 1; off < 16; off <<= 1) {
        a0 += __shfl_xor(a0, off);
        a1 += __shfl_xor(a1, off);
        a2 += __shfl_xor(a2, off);
        a3 += __shfl_xor(a3, off);
    }
    if (q < 8) {
        float a[4] = {a0, a1, a2, a3};
        float v = ldf(b1, q, isbf);
#pragma unroll
        for (int c = 0; c < 4; ++c)
            v += a[c] * ldf(W1r, c * 8 + q, isbf)
               + ldf(xg, d * 4 + c, isbf) * ldf(W1o, c * 8 + q, isbf);
        hbf[d * 8 + q] = f2bfbits(selu_f(v));
    }
}

// ---- Gather+Node 2 fused: 16 threads/dst; lane q -> output j=q ------------
__global__ __launch_bounds__(256) void k_gather2(const int* __restrict__ dstoff,
        const int* __restrict__ ddeg, const unsigned int* __restrict__ glist,
        const ushortx8* __restrict__ hbf,
        const void* __restrict__ W2r, const void* __restrict__ W2o,
        const void* __restrict__ b2, unsigned short* __restrict__ xs,
        const int* __restrict__ flags) {
    int gid = blockIdx.x * 256 + threadIdx.x;
    int d = gid >> 4;
    if (d >= NG) return;
    int q = gid & 15;
    int isbf = flags[0];
    int start = dstoff[d];
    int deg = ddeg[d];
    float a[8] = {0.f, 0.f, 0.f, 0.f, 0.f, 0.f, 0.f, 0.f};
    int k = q;
    for (; k + 16 < deg; k += 32) {
        int s0 = glist[start + k];
        int s1 = glist[start + k + 16];
        ushortx8 r0 = hbf[s0];
        ushortx8 r1 = hbf[s1];
#pragma unroll
        for (int c = 0; c < 8; ++c)
            a[c] += bfbits2f((unsigned short)r0[c]) + bfbits2f((unsigned short)r1[c]);
    }
    for (; k < deg; k += 16) {
        int s = glist[start + k];
        ushortx8 r = hbf[s];
#pragma unroll
        for (int c = 0; c < 8; ++c) a[c] += bfbits2f((unsigned short)r[c]);
    }
#pragma unroll
    for (int off = 1; off < 16; off <<= 1) {
#pragma unroll
        for (int c = 0; c < 8; ++c) a[c] += __shfl_xor(a[c], off);
    }
    ushortx8 hr = hbf[d];
    float hv[8];
#pragma unroll
    for (int c = 0; c < 8; ++c) hv[c] = bfbits2f((unsigned short)hr[c]);
    float v = ldf(b2, q, isbf);
#pragma unroll
    for (int c = 0; c < 8; ++c)
        v += a[c] * ldf(W2r, c * 16 + q, isbf)
           + hv[c] * ldf(W2o, c * 16 + q, isbf);
    xs[d * 16 + q] = f2bfbits(selu_f(v));
}

// ---- fc_unconnected -> x_stacked[NG:NG+NU] (bf16), NO selu ----------------
__global__ __launch_bounds__(256) void k_unconn(const void* __restrict__ xu,
        const void* __restrict__ Wun, const void* __restrict__ bun,
        unsigned short* __restrict__ xs, const int* __restrict__ flags) {
    int u = blockIdx.x * 256 + threadIdx.x;
    if (u >= NU) return;
    int isbf = flags[0];
    float x[4];
#pragma unroll
    for (int k = 0; k < 4; ++k) x[k] = ldf(xu, u * 4 + k, isbf);
    ushortx8 lo, hi;
#pragma unroll
    for (int j = 0; j < 16; ++j) {
        float v = ldf(bun, j, isbf);
#pragma unroll
        for (int k = 0; k < 4; ++k)
            v += x[k] * ldf(Wun, k * 16 + j, isbf);
        unsigned short bb = f2bfbits(v);
        if (j < 8) lo[j] = bb; else hi[j - 8] = bb;
    }
    ushortx8* xp = (ushortx8*)(xs + (NG + u) * 16);
    xp[0] = lo;
    xp[1] = hi;
}

__device__ __forceinline__ int2 ld_cand2(const void* cand, int c, int c64) {
    if (c64) {
        const long long* cl = (const long long*)cand;
        return make_int2((int)cl[2 * c], (int)cl[2 * c + 1]);
    }
    return *(const int2*)((const int*)cand + 2 * c);
}

// ---- FC head: persistent waves, 3-deep software-pipelined gather.
//      TRANSPOSED MFMA with L2E pre-folded (ac = L2E*v); epilogue per hidden
//      unit: contrib = w2s * (max(ac,0) + AR2*exp2(min(ac,0))), constant term
//      in c_corr. R4: 4 independent per-tt accumulators (dep chain 32->8
//      fmas -- R3 showed VALUBusy 51% with a serial part chain), 3-deep af
//      pipeline, grid 1024 blocks (4096 waves ~= measured residency at
//      OccupancyPercent 40%; avoids the two-generation drain of 8192 waves).
__global__ __launch_bounds__(256, 5) void k_fc(const unsigned short* __restrict__ xs,
        const void* __restrict__ cand,
        const void* __restrict__ Wfc1, const void* __restrict__ bfc1,
        const void* __restrict__ Wfc2, const void* __restrict__ bfc2,
        void* __restrict__ out, const int* __restrict__ flags) {
    const float LAM = 1.0507009873554805f;
    const float ALA = 1.7580993408473766f;  // LAM * ALPHA
    const float L2E = 1.44269504088896340736f;
    const float AR2 = 1.6732632423543772f * 1.44269504088896340736f;  // ALPHA*L2E
    const float SCL = 1.0507009873554805f / 1.44269504088896340736f;  // LAM/L2E
    int lane = threadIdx.x & 63;
    int wid = (blockIdx.x * blockDim.x + threadIdx.x) >> 6;
    int m = lane & 15;
    int half = lane >> 4;
    int isbf = flags[0], c64 = flags[1];

    short8 wfrag[4];
    floatx4 cbias[4];
    float w2s[4][4];
    float c_corr;
    if (isbf) {
        const unsigned short* W1p = (const unsigned short*)Wfc1;
#pragma unroll
        for (int t = 0; t < 4; ++t)
#pragma unroll
            for (int j = 0; j < 8; ++j)
                wfrag[t][j] = (short)f2bfbits(
                    bfbits2f(W1p[(half * 8 + j) * 64 + t * 16 + m]) * L2E);
        const unsigned short* b1p = (const unsigned short*)bfc1;
        const unsigned short* w2p = (const unsigned short*)Wfc2;
        float asum = 0.f;
#pragma unroll
        for (int t = 0; t < 4; ++t)
#pragma unroll
            for (int r = 0; r < 4; ++r) {
                int h = t * 16 + half * 4 + r;
                cbias[t][r] = bfbits2f(b1p[h]) * L2E;
                float w2 = bfbits2f(w2p[h]);
                w2s[t][r] = w2 * SCL;
                asum += w2 * ALA;
            }
        asum += __shfl_xor(asum, 16, 64);
        asum += __shfl_xor(asum, 32, 64);
        c_corr = bfbits2f(((const unsigned short*)bfc2)[0]) - asum;
    } else {
        const float* W1p = (const float*)Wfc1;
#pragma unroll
        for (int t = 0; t < 4; ++t)
#pragma unroll
            for (int j = 0; j < 8; ++j)
                wfrag[t][j] = (short)f2bfbits(
                    W1p[(half * 8 + j) * 64 + t * 16 + m] * L2E);
        const float* b1p = (const float*)bfc1;
        const float* w2p = (const float*)Wfc2;
        float asum = 0.f;
#pragma unroll
        for (int t = 0; t < 4; ++t)
#pragma unroll
            for (int r = 0; r < 4; ++r) {
                int h = t * 16 + half * 4 + r;
                cbias[t][r] = b1p[h] * L2E;
                float w2 = w2p[h];
                w2s[t][r] = w2 * SCL;
                asum += w2 * ALA;
            }
        asum += __shfl_xor(asum, 16, 64);
        asum += __shfl_xor(asum, 32, 64);
        c_corr = ((const float*)bfc2)[0] - asum;
    }

    const int nTiles = NC / 16;
    int nW = (gridDim.x * blockDim.x) >> 6;
    if (wid >= nTiles) return;

    // 3-deep gather pipeline: af for tiles t, t+nW, t+2nW in flight; cand 4
    // ahead in the cc queue.
    int half1 = half & 1;
    int t1 = wid + nW, t2 = wid + 2 * nW, t3 = wid + 3 * nW;
    int2 cc0 = ld_cand2(cand, wid * 16 + m, c64);
    int2 cc1 = ld_cand2(cand, ((t1 < nTiles) ? t1 : wid) * 16 + m, c64);
    int2 cc2 = ld_cand2(cand, ((t2 < nTiles) ? t2 : wid) * 16 + m, c64);
    int2 cc3 = ld_cand2(cand, ((t3 < nTiles) ? t3 : wid) * 16 + m, c64);
    {
        int row0 = (half < 2) ? cc0.x : cc0.y;
        short8 af0 = *(const short8*)(xs + row0 * 16 + half1 * 8);
        int row1 = (half < 2) ? cc1.x : cc1.y;
        short8 af1 = *(const short8*)(xs + row1 * 16 + half1 * 8);
        int row2 = (half < 2) ? cc2.x : cc2.y;
        short8 af2 = *(const short8*)(xs + row2 * 16 + half1 * 8);

#pragma unroll 3
        for (int t = wid; t < nTiles; t += nW) {
            int tn4 = t + 4 * nW;
            int2 cc4 = ld_cand2(cand, ((tn4 < nTiles) ? tn4 : t) * 16 + m, c64);
            int row3 = (half < 2) ? cc3.x : cc3.y;
            short8 af3 = *(const short8*)(xs + row3 * 16 + half1 * 8);

            float ps[4];
#pragma unroll
            for (int tt = 0; tt < 4; ++tt) {
                floatx4 ac = __builtin_amdgcn_mfma_f32_16x16x32_bf16(
                    wfrag[tt], af0, cbias[tt], 0, 0, 0);
                float s = 0.f;
#pragma unroll
                for (int r = 0; r < 4; ++r) {
                    float v = ac[r];
                    float mx = fmaxf(v, 0.f);
                    float e = __builtin_amdgcn_exp2f(fminf(v, 0.f));
                    s = fmaf(w2s[tt][r], fmaf(AR2, e, mx), s);
                }
                ps[tt] = s;
            }
            float part = (ps[0] + ps[1]) + (ps[2] + ps[3]);
            part += __shfl_xor(part, 16, 64);
            part += __shfl_xor(part, 32, 64);
            if (half == 0) {
                float o = part + c_corr;
                if (isbf) ((unsigned short*)out)[t * 16 + m] = f2bfbits(o);
                else ((float*)out)[t * 16 + m] = o;
            }
            af0 = af1;
            af1 = af2;
            af2 = af3;
            cc3 = cc4;
        }
    }
}

extern "C" void kernel_launch(void* const* d_in, const int* in_sizes, int n_in,
                              void* d_out, int out_size, void* d_ws, size_t ws_size,
                              hipStream_t stream) {
    const void* x_u = d_in[0];
    const void* x_g = d_in[1];
    const void* cand = d_in[2];
    const void* edges = d_in[3];
    const void* W1r = d_in[4];
    const void* W1o = d_in[5];
    const void* b1 = d_in[6];
    const void* W2r = d_in[7];
    const void* W2o = d_in[8];
    const void* b2 = d_in[9];
    const void* Wun = d_in[10];
    const void* bun = d_in[11];
    const void* Wfc1 = d_in[12];
    const void* bfc1 = d_in[13];
    const void* Wfc2 = d_in[14];
    const void* bfc2 = d_in[15];

    char* ws = (char*)d_ws;
    int* flags = (int*)ws;                                  // 64 B
    int* gcur = (int*)(ws + 64);                            // 782*4 -> 3200 B
    int* scur = (int*)(ws + 3264);                          // 61*4  -> 244 B
    unsigned int* glist = (unsigned int*)(ws + 4160);       // 16.01 MB
    size_t glist_bytes = (size_t)NBK * CAP * 4;             // 16010240
    char* p = ws + 4160 + glist_bytes;
    // slist (13.75 MB) overlaps the post-binning buffers: dead after k_bin2.
    unsigned int* slist = (unsigned int*)p;                 // 61*56320*4 = 13.74 MB
    int* dstoff = (int*)p;                                  // 400 KB
    int* ddeg = (int*)(p + 400000);                         // 400 KB
    unsigned short* hbf = (unsigned short*)(p + 800000);    // 1.6 MB
    unsigned short* xs = (unsigned short*)(p + 2400000);    // 6.4 MB

    hipMemsetAsync(gcur, 0, 3456, stream);   // zeroes gcur + scur

    k_detect<<<1, 64, 0, stream>>>((const unsigned int*)x_u,
                                   (const unsigned int*)cand,
                                   (const unsigned int*)edges, flags);
    k_bin1<<<(NE + B1CH - 1) / B1CH, 256, 0, stream>>>(edges, scur, slist, flags);
    k_bin2<<<NSUP * SCH2, 256, 0, stream>>>(scur, slist, gcur, glist);
    k_sort<<<NBK, 256, 0, stream>>>(gcur, glist, dstoff, ddeg);
    k_gather1<<<(16 * NG + 255) / 256, 256, 0, stream>>>(dstoff, ddeg, glist, x_g,
                                                         W1r, W1o, b1, hbf, flags);
    k_gather2<<<(16 * NG + 255) / 256, 256, 0, stream>>>(dstoff, ddeg, glist,
                                                         (const ushortx8*)hbf,
                                                         W2r, W2o, b2, xs, flags);
    k_unconn<<<(NU + 255) / 256, 256, 0, stream>>>(x_u, Wun, bun, xs, flags);
    k_fc<<<1024, 256, 0, stream>>>(xs, cand, Wfc1, bfc1, Wfc2, bfc2, d_out, flags);
}

// Round 5
// 268.688 us; speedup vs baseline: 1.0446x; 1.0135x over previous
//
#include <hip/hip_runtime.h>
#include <hip/hip_bf16.h>

#define NG 100000
#define NU 100000
#define NE 3200000
#define NC 2000000

// dst-bucket binning: 128 dsts per bucket
#define BSZ 128
#define NBK 782          // ceil(NG/BSZ)
#define CAP 5120         // entries per fine bucket (mean 4096, +16 sigma)

// two-level binning: 61 super-buckets of 13 fine buckets (61*13=793>=782)
#define NSUP 61
#define SFB 13
#define SSPAN (SFB * BSZ)   // 1664 dsts per super
#define SCAP 56320          // entries per super (mean 52459, +17 sigma)
#define B1CH 4096           // edges per bin1 block (LDS-staged single read)
#define B2CH 4096           // entries per bin2 block

typedef __attribute__((ext_vector_type(8))) short short8;
typedef __attribute__((ext_vector_type(4))) float floatx4;
typedef unsigned short ushortx8 __attribute__((ext_vector_type(8)));

// branchless SELU on the HW transcendental (6 VALU ops)
__device__ __forceinline__ float selu_f(float x) {
    const float LAM = 1.0507009873554805f;
    const float ALA = 1.7580993408473766f;  // LAM * ALPHA
    const float L2E = 1.44269504088896340736f;
    float e = __builtin_amdgcn_exp2f(fminf(x, 0.f) * L2E);
    return fmaf(LAM, fmaxf(x, 0.f), fmaf(ALA, e, -ALA));
}

__device__ __forceinline__ float bfbits2f(unsigned short u) {
    return __uint_as_float(((unsigned)u) << 16);
}

__device__ __forceinline__ unsigned short f2bfbits(float f) {
    union { __hip_bfloat16 h; unsigned short u; } cv;
    cv.h = __float2bfloat16(f);
    return cv.u;
}

__device__ __forceinline__ float ldf(const void* p, int i, int isbf) {
    return isbf ? bfbits2f(((const unsigned short*)p)[i]) : ((const float*)p)[i];
}

// ---- dtype detection ------------------------------------------------------
__global__ void k_detect(const unsigned int* __restrict__ xw,
                         const unsigned int* __restrict__ cw,
                         const unsigned int* __restrict__ ew,
                         int* __restrict__ flags) {
    if (threadIdx.x != 0 || blockIdx.x != 0) return;
    int nb = 0;
    for (int i = 0; i < 64; ++i) {
        unsigned lo = xw[i] & 0xffffu;
        unsigned e = (lo >> 7) & 0xff;
        if (e >= 112 && e <= 134) ++nb;
    }
    flags[0] = (nb >= 32) ? 1 : 0;
    int cz = 0, ez = 0;
    for (int i = 0; i < 64; ++i) {
        if (cw[2 * i + 1] == 0u) ++cz;
        if (ew[2 * i + 1] == 0u) ++ez;
    }
    flags[1] = (cz >= 48) ? 1 : 0;
    flags[2] = (ez >= 48) ? 1 : 0;
}

__device__ __forceinline__ void ld_edge(const void* edges, long long e, int e64,
                                        int& s, int& d) {
    if (e64) {
        const long long* el = (const long long*)edges;
        s = (int)el[e];
        d = (int)el[NE + e];
    } else {
        const int* ei = (const int*)edges;
        s = ei[e];
        d = ei[NE + e];
    }
}

// ---- Binning pass 1: edges -> 61 super-buckets. SINGLE global read:
//      entries staged in LDS during the histogram pass. Runs ~67 entries
//      (268 B) at 61 buckets -> still fully coalesced writes. --------------
__global__ __launch_bounds__(256) void k_bin1(const void* __restrict__ edges,
        int* __restrict__ scur, unsigned int* __restrict__ slist,
        const int* __restrict__ flags) {
    __shared__ unsigned int tmp[B1CH];         // 16 KB  (s<<11)|dlocal
    __shared__ unsigned char tsup[B1CH];       // 4 KB
    __shared__ unsigned int ord[B1CH];         // 16 KB
    __shared__ unsigned char osup[B1CH];       // 4 KB
    __shared__ int hist[64];
    __shared__ int lstart[64];
    __shared__ int ofs[64];
    __shared__ int gbase[64];                  // ~41 KB -> 3 blocks/CU

    int tid = threadIdx.x;
    long long base = (long long)blockIdx.x * B1CH;
    int chunk = (int)(NE - base);
    if (chunk > B1CH) chunk = B1CH;
    int e64 = flags[2];

    if (tid < 64) hist[tid] = 0;
    __syncthreads();

    // phase A: single global read -> LDS stage + histogram
    for (int i = 0; i < B1CH / 256; ++i) {
        int idx = i * 256 + tid;
        if (idx < chunk) {
            int s, d;
            ld_edge(edges, base + idx, e64, s, d);
            int sup = d / SSPAN;
            tmp[idx] = ((unsigned)s << 11) | (unsigned)(d - sup * SSPAN);
            tsup[idx] = (unsigned char)sup;
            atomicAdd(&hist[sup], 1);
        }
    }
    __syncthreads();

    // phase B: serial scan (61) + global reservation
    if (tid == 0) {
        int run = 0;
        for (int b = 0; b < NSUP; ++b) {
            lstart[b] = run;
            run += hist[b];
        }
    }
    __syncthreads();
    if (tid < NSUP) {
        int c = hist[tid];
        int g = 0;
        if (c > 0) g = atomicAdd(&scur[tid], c);
        gbase[tid] = g;
        ofs[tid] = lstart[tid];
    }
    __syncthreads();

    // phase C: reorder within LDS
    for (int i = 0; i < B1CH / 256; ++i) {
        int idx = i * 256 + tid;
        if (idx < chunk) {
            int sup = tsup[idx];
            int pos = atomicAdd(&ofs[sup], 1);
            ord[pos] = tmp[idx];
            osup[pos] = (unsigned char)sup;
        }
    }
    __syncthreads();

    // phase D: coalesced write-out
    for (int i = 0; i < B1CH / 256; ++i) {
        int idx = i * 256 + tid;
        if (idx < chunk) {
            int sup = osup[idx];
            int p = gbase[sup] + (idx - lstart[sup]);
            if (p < SCAP) slist[(long long)sup * SCAP + p] = ord[idx];
        }
    }
}

#define SCH2 ((SCAP + B2CH - 1) / B2CH)   // 14 chunks per super

// ---- Binning pass 2: super -> 13 fine buckets. SINGLE slist read. --------
__global__ __launch_bounds__(256) void k_bin2(const int* __restrict__ scur,
        const unsigned int* __restrict__ slist,
        int* __restrict__ gcur, unsigned int* __restrict__ glist) {
    __shared__ unsigned int tmp[B2CH];         // 16 KB
    __shared__ unsigned int ord[B2CH];         // 16 KB
    __shared__ unsigned char ofid[B2CH];       // 4 KB
    __shared__ int hist[16];
    __shared__ int lstart[16];
    __shared__ int ofs[16];
    __shared__ int gbase[16];                  // ~36.5 KB -> 4 blocks/CU

    int tid = threadIdx.x;
    int sup = blockIdx.x / SCH2;
    int ch = blockIdx.x % SCH2;
    int scnt = scur[sup];
    if (scnt > SCAP) scnt = SCAP;
    int start = ch * B2CH;
    int cnt = scnt - start;
    if (cnt <= 0) return;
    if (cnt > B2CH) cnt = B2CH;
    const unsigned int* sp = slist + (long long)sup * SCAP + start;

    if (tid < 16) hist[tid] = 0;
    __syncthreads();

    // phase A: single global read -> LDS stage + histogram
    for (int i = 0; i < B2CH / 256; ++i) {
        int idx = i * 256 + tid;
        if (idx < cnt) {
            unsigned u = sp[idx];
            tmp[idx] = u;
            atomicAdd(&hist[(u & 2047) >> 7], 1);
        }
    }
    __syncthreads();

    if (tid == 0) {
        int run = 0;
        for (int b = 0; b < SFB; ++b) {
            lstart[b] = run;
            run += hist[b];
        }
    }
    __syncthreads();
    if (tid < SFB) {
        int c = hist[tid];
        int g = 0;
        int bf = sup * SFB + tid;
        if (c > 0 && bf < NBK) g = atomicAdd(&gcur[bf], c);
        gbase[tid] = g;
        ofs[tid] = lstart[tid];
    }
    __syncthreads();

    // phase C: reorder within LDS (convert to (s<<7)|dl127)
    for (int i = 0; i < B2CH / 256; ++i) {
        int idx = i * 256 + tid;
        if (idx < cnt) {
            unsigned u = tmp[idx];
            int dl = u & 2047;
            int f = dl >> 7;
            int pos = atomicAdd(&ofs[f], 1);
            ord[pos] = ((u >> 11) << 7) | (unsigned)(dl & 127);
            ofid[pos] = (unsigned char)f;
        }
    }
    __syncthreads();

    // phase D: coalesced write-out (runs ~315 entries)
    for (int i = 0; i < B2CH / 256; ++i) {
        int idx = i * 256 + tid;
        if (idx < cnt) {
            int f = ofid[idx];
            int bf = sup * SFB + f;
            int p = gbase[f] + (idx - lstart[f]);
            if (p < CAP) glist[(long long)bf * CAP + p] = ord[idx];
        }
    }
}

// ---- Counting-sort each bucket by dl. SINGLE glist read (LDS-staged),
//      in-place write-back; emits per-dst CSR. -----------------------------
__global__ __launch_bounds__(256) void k_sort(const int* __restrict__ gcur,
        unsigned int* __restrict__ glist,
        int* __restrict__ dstoff, int* __restrict__ ddeg) {
    __shared__ unsigned int tmp[CAP];      // 20 KB
    __shared__ unsigned int sorted[CAP];   // 20 KB
    __shared__ int hist[BSZ];
    __shared__ int incl[BSZ];
    __shared__ int cur[BSZ];               // ~41.5 KB -> 3 blocks/CU
    int b = blockIdx.x;
    int tid = threadIdx.x;
    int cnt = gcur[b];
    if (cnt > CAP) cnt = CAP;
    unsigned int* lp = glist + (long long)b * CAP;

    if (tid < BSZ) hist[tid] = 0;
    __syncthreads();
    // single global read -> LDS + histogram
    for (int k = tid; k < cnt; k += 256) {
        unsigned u = lp[k];
        tmp[k] = u;
        atomicAdd(&hist[u & 127], 1);
    }
    __syncthreads();
    if (tid < BSZ) incl[tid] = hist[tid];
    __syncthreads();
    for (int off = 1; off < BSZ; off <<= 1) {
        int v = (tid < BSZ && tid >= off) ? incl[tid - off] : 0;
        __syncthreads();
        if (tid < BSZ && tid >= off) incl[tid] += v;
        __syncthreads();
    }
    if (tid < BSZ) {
        int excl = incl[tid] - hist[tid];
        cur[tid] = excl;
        int d = b * BSZ + tid;
        if (d < NG) {
            dstoff[d] = b * CAP + excl;
            ddeg[d] = hist[tid];
        }
    }
    __syncthreads();
    for (int k = tid; k < cnt; k += 256) {
        unsigned u = tmp[k];
        int pos = atomicAdd(&cur[u & 127], 1);
        sorted[pos] = u >> 7;
    }
    __syncthreads();
    for (int k = tid; k < cnt; k += 256) lp[k] = sorted[k];
}

// ---- Gather+Node 1 fused: 16 threads/dst, paired independent gathers.
//      isbf hoisted out of the edge loop (wave-uniform). -------------------
__global__ __launch_bounds__(256) void k_gather1(const int* __restrict__ dstoff,
        const int* __restrict__ ddeg, const unsigned int* __restrict__ glist,
        const void* __restrict__ xg,
        const void* __restrict__ W1r, const void* __restrict__ W1o,
        const void* __restrict__ b1, unsigned short* __restrict__ hbf,
        const int* __restrict__ flags) {
    int gid = blockIdx.x * 256 + threadIdx.x;
    int d = gid >> 4;
    if (d >= NG) return;
    int q = gid & 15;
    int isbf = flags[0];
    int start = dstoff[d];
    int deg = ddeg[d];
    float a0 = 0.f, a1 = 0.f, a2 = 0.f, a3 = 0.f;
    if (isbf) {
        const unsigned short* xp = (const unsigned short*)xg;
        int k = q;
        for (; k + 16 < deg; k += 32) {
            int s0 = glist[start + k];
            int s1 = glist[start + k + 16];
            ushort4 r0 = *(const ushort4*)(xp + s0 * 4);
            ushort4 r1 = *(const ushort4*)(xp + s1 * 4);
            a0 += bfbits2f(r0.x) + bfbits2f(r1.x);
            a1 += bfbits2f(r0.y) + bfbits2f(r1.y);
            a2 += bfbits2f(r0.z) + bfbits2f(r1.z);
            a3 += bfbits2f(r0.w) + bfbits2f(r1.w);
        }
        for (; k < deg; k += 16) {
            int s = glist[start + k];
            ushort4 r = *(const ushort4*)(xp + s * 4);
            a0 += bfbits2f(r.x); a1 += bfbits2f(r.y);
            a2 += bfbits2f(r.z); a3 += bfbits2f(r.w);
        }
    } else {
        const float* xp = (const float*)xg;
        int k = q;
        for (; k + 16 < deg; k += 32) {
            int s0 = glist[start + k];
            int s1 = glist[start + k + 16];
            float4 r0 = *(const float4*)(xp + s0 * 4);
            float4 r1 = *(const float4*)(xp + s1 * 4);
            a0 += r0.x + r1.x;
            a1 += r0.y + r1.y;
            a2 += r0.z + r1.z;
            a3 += r0.w + r1.w;
        }
        for (; k < deg; k += 16) {
            int s = glist[start + k];
            float4 r = *(const float4*)(xp + s * 4);
            a0 += r.x; a1 += r.y; a2 += r.z; a3 += r.w;
        }
    }
#pragma unroll
    for (int off = 1; off < 16; off <<= 1) {
        a0 += __shfl_xor(a0, off);
        a1 += __shfl_xor(a1, off);
        a2 += __shfl_xor(a2, off);
        a3 += __shfl_xor(a3, off);
    }
    if (q < 8) {
        float a[4] = {a0, a1, a2, a3};
        float v = ldf(b1, q, isbf);
#pragma unroll
        for (int c = 0; c < 4; ++c)
            v += a[c] * ldf(W1r, c * 8 + q, isbf)
               + ldf(xg, d * 4 + c, isbf) * ldf(W1o, c * 8 + q, isbf);
        hbf[d * 8 + q] = f2bfbits(selu_f(v));
    }
}

// ---- Gather+Node 2 fused: 16 threads/dst; lane q -> output j=q ------------
__global__ __launch_bounds__(256) void k_gather2(const int* __restrict__ dstoff,
        const int* __restrict__ ddeg, const unsigned int* __restrict__ glist,
        const ushortx8* __restrict__ hbf,
        const void* __restrict__ W2r, const void* __restrict__ W2o,
        const void* __restrict__ b2, unsigned short* __restrict__ xs,
        const int* __restrict__ flags) {
    int gid = blockIdx.x * 256 + threadIdx.x;
    int d = gid >> 4;
    if (d >= NG) return;
    int q = gid & 15;
    int isbf = flags[0];
    int start = dstoff[d];
    int deg = ddeg[d];
    float a[8] = {0.f, 0.f, 0.f, 0.f, 0.f, 0.f, 0.f, 0.f};
    int k = q;
    for (; k + 16 < deg; k += 32) {
        int s0 = glist[start + k];
        int s1 = glist[start + k + 16];
        ushortx8 r0 = hbf[s0];
        ushortx8 r1 = hbf[s1];
#pragma unroll
        for (int c = 0; c < 8; ++c)
            a[c] += bfbits2f((unsigned short)r0[c]) + bfbits2f((unsigned short)r1[c]);
    }
    for (; k < deg; k += 16) {
        int s = glist[start + k];
        ushortx8 r = hbf[s];
#pragma unroll
        for (int c = 0; c < 8; ++c) a[c] += bfbits2f((unsigned short)r[c]);
    }
#pragma unroll
    for (int off = 1; off < 16; off <<= 1) {
#pragma unroll
        for (int c = 0; c < 8; ++c) a[c] += __shfl_xor(a[c], off);
    }
    ushortx8 hr = hbf[d];
    float hv[8];
#pragma unroll
    for (int c = 0; c < 8; ++c) hv[c] = bfbits2f((unsigned short)hr[c]);
    float v = ldf(b2, q, isbf);
#pragma unroll
    for (int c = 0; c < 8; ++c)
        v += a[c] * ldf(W2r, c * 16 + q, isbf)
           + hv[c] * ldf(W2o, c * 16 + q, isbf);
    xs[d * 16 + q] = f2bfbits(selu_f(v));
}

// ---- fc_unconnected -> x_stacked[NG:NG+NU] (bf16), NO selu ----------------
__global__ __launch_bounds__(256) void k_unconn(const void* __restrict__ xu,
        const void* __restrict__ Wun, const void* __restrict__ bun,
        unsigned short* __restrict__ xs, const int* __restrict__ flags) {
    int u = blockIdx.x * 256 + threadIdx.x;
    if (u >= NU) return;
    int isbf = flags[0];
    float x[4];
#pragma unroll
    for (int k = 0; k < 4; ++k) x[k] = ldf(xu, u * 4 + k, isbf);
    ushortx8 lo, hi;
#pragma unroll
    for (int j = 0; j < 16; ++j) {
        float v = ldf(bun, j, isbf);
#pragma unroll
        for (int k = 0; k < 4; ++k)
            v += x[k] * ldf(Wun, k * 16 + j, isbf);
        unsigned short bb = f2bfbits(v);
        if (j < 8) lo[j] = bb; else hi[j - 8] = bb;
    }
    ushortx8* xp = (ushortx8*)(xs + (NG + u) * 16);
    xp[0] = lo;
    xp[1] = hi;
}

// per-lane candidate ROW index: lane half-group hp=half>>1 selects endpoint.
// c64: low 32 bits of int64 little-endian at int-index 2*(2c+hp).
__device__ __forceinline__ int ld_candrow(const void* cand, int c, int hp, int c64) {
    const int* ci = (const int*)cand;
    return c64 ? ci[(2 * c + hp) * 2] : ci[2 * c + hp];
}

// ---- FC head: persistent waves, 4-deep software-pipelined gather.
//      TRANSPOSED MFMA with L2E pre-folded (ac = L2E*v); epilogue per hidden
//      unit: contrib = w2s * (max(ac,0) + AR2*exp2(min(ac,0))); constant term
//      in c_corr. R5: k_fc is memory-LATENCY-bound on the scattered xs
//      gather (R4: issue-work ~30K cyc/SIMD vs 130K wall; VALUBusy counter
//      inflated ~2x by the gfx94x derived formula on SIMD-32). Raise MLP:
//      depth 3->4 in-flight gathers/wave, grid 1280 blocks = 5120 waves =
//      exactly 5 waves/SIMD (one generation, matches (256,5) reg budget).
//      Cand fetch: direct per-lane 4B row-index load (no int2+cndmask). ----
__global__ __launch_bounds__(256, 5) void k_fc(const unsigned short* __restrict__ xs,
        const void* __restrict__ cand,
        const void* __restrict__ Wfc1, const void* __restrict__ bfc1,
        const void* __restrict__ Wfc2, const void* __restrict__ bfc2,
        void* __restrict__ out, const int* __restrict__ flags) {
    const float LAM = 1.0507009873554805f;
    const float ALA = 1.7580993408473766f;  // LAM * ALPHA
    const float L2E = 1.44269504088896340736f;
    const float AR2 = 1.6732632423543772f * 1.44269504088896340736f;  // ALPHA*L2E
    const float SCL = 1.0507009873554805f / 1.44269504088896340736f;  // LAM/L2E
    int lane = threadIdx.x & 63;
    int wid = (blockIdx.x * blockDim.x + threadIdx.x) >> 6;
    int m = lane & 15;
    int half = lane >> 4;
    int isbf = flags[0], c64 = flags[1];

    short8 wfrag[4];
    floatx4 cbias[4];
    float w2s[4][4];
    float c_corr;
    if (isbf) {
        const unsigned short* W1p = (const unsigned short*)Wfc1;
#pragma unroll
        for (int t = 0; t < 4; ++t)
#pragma unroll
            for (int j = 0; j < 8; ++j)
                wfrag[t][j] = (short)f2bfbits(
                    bfbits2f(W1p[(half * 8 + j) * 64 + t * 16 + m]) * L2E);
        const unsigned short* b1p = (const unsigned short*)bfc1;
        const unsigned short* w2p = (const unsigned short*)Wfc2;
        float asum = 0.f;
#pragma unroll
        for (int t = 0; t < 4; ++t)
#pragma unroll
            for (int r = 0; r < 4; ++r) {
                int h = t * 16 + half * 4 + r;
                cbias[t][r] = bfbits2f(b1p[h]) * L2E;
                float w2 = bfbits2f(w2p[h]);
                w2s[t][r] = w2 * SCL;
                asum += w2 * ALA;
            }
        asum += __shfl_xor(asum, 16, 64);
        asum += __shfl_xor(asum, 32, 64);
        c_corr = bfbits2f(((const unsigned short*)bfc2)[0]) - asum;
    } else {
        const float* W1p = (const float*)Wfc1;
#pragma unroll
        for (int t = 0; t < 4; ++t)
#pragma unroll
            for (int j = 0; j < 8; ++j)
                wfrag[t][j] = (short)f2bfbits(
                    W1p[(half * 8 + j) * 64 + t * 16 + m] * L2E);
        const float* b1p = (const float*)bfc1;
        const float* w2p = (const float*)Wfc2;
        float asum = 0.f;
#pragma unroll
        for (int t = 0; t < 4; ++t)
#pragma unroll
            for (int r = 0; r < 4; ++r) {
                int h = t * 16 + half * 4 + r;
                cbias[t][r] = b1p[h] * L2E;
                float w2 = w2p[h];
                w2s[t][r] = w2 * SCL;
                asum += w2 * ALA;
            }
        asum += __shfl_xor(asum, 16, 64);
        asum += __shfl_xor(asum, 32, 64);
        c_corr = ((const float*)bfc2)[0] - asum;
    }

    const int nTiles = NC / 16;
    int nW = (gridDim.x * blockDim.x) >> 6;
    if (wid >= nTiles) return;

    int half1 = half & 1;
    int hp = half >> 1;
    // 4-deep gather pipeline: af for tiles t..t+3nW in flight; row-index
    // queue one tile further ahead.
    int t1 = wid + nW, t2 = wid + 2 * nW, t3 = wid + 3 * nW, t4 = wid + 4 * nW;
    int r0i = ld_candrow(cand, wid * 16 + m, hp, c64);
    int r1i = ld_candrow(cand, ((t1 < nTiles) ? t1 : wid) * 16 + m, hp, c64);
    int r2i = ld_candrow(cand, ((t2 < nTiles) ? t2 : wid) * 16 + m, hp, c64);
    int r3i = ld_candrow(cand, ((t3 < nTiles) ? t3 : wid) * 16 + m, hp, c64);
    int r4i = ld_candrow(cand, ((t4 < nTiles) ? t4 : wid) * 16 + m, hp, c64);
    {
        short8 af0 = *(const short8*)(xs + r0i * 16 + half1 * 8);
        short8 af1 = *(const short8*)(xs + r1i * 16 + half1 * 8);
        short8 af2 = *(const short8*)(xs + r2i * 16 + half1 * 8);
        short8 af3 = *(const short8*)(xs + r3i * 16 + half1 * 8);

#pragma unroll 2
        for (int t = wid; t < nTiles; t += nW) {
            int tn5 = t + 5 * nW;
            int r5i = ld_candrow(cand, ((tn5 < nTiles) ? tn5 : t) * 16 + m, hp, c64);
            short8 af4 = *(const short8*)(xs + r4i * 16 + half1 * 8);

            float ps[4];
#pragma unroll
            for (int tt = 0; tt < 4; ++tt) {
                floatx4 ac = __builtin_amdgcn_mfma_f32_16x16x32_bf16(
                    wfrag[tt], af0, cbias[tt], 0, 0, 0);
                float s = 0.f;
#pragma unroll
                for (int r = 0; r < 4; ++r) {
                    float v = ac[r];
                    float mx = fmaxf(v, 0.f);
                    float e = __builtin_amdgcn_exp2f(fminf(v, 0.f));
                    s = fmaf(w2s[tt][r], fmaf(AR2, e, mx), s);
                }
                ps[tt] = s;
            }
            float part = (ps[0] + ps[1]) + (ps[2] + ps[3]);
            part += __shfl_xor(part, 16, 64);
            part += __shfl_xor(part, 32, 64);
            if (half == 0) {
                float o = part + c_corr;
                if (isbf) ((unsigned short*)out)[t * 16 + m] = f2bfbits(o);
                else ((float*)out)[t * 16 + m] = o;
            }
            af0 = af1;
            af1 = af2;
            af2 = af3;
            af3 = af4;
            r4i = r5i;
        }
    }
}

extern "C" void kernel_launch(void* const* d_in, const int* in_sizes, int n_in,
                              void* d_out, int out_size, void* d_ws, size_t ws_size,
                              hipStream_t stream) {
    const void* x_u = d_in[0];
    const void* x_g = d_in[1];
    const void* cand = d_in[2];
    const void* edges = d_in[3];
    const void* W1r = d_in[4];
    const void* W1o = d_in[5];
    const void* b1 = d_in[6];
    const void* W2r = d_in[7];
    const void* W2o = d_in[8];
    const void* b2 = d_in[9];
    const void* Wun = d_in[10];
    const void* bun = d_in[11];
    const void* Wfc1 = d_in[12];
    const void* bfc1 = d_in[13];
    const void* Wfc2 = d_in[14];
    const void* bfc2 = d_in[15];

    char* ws = (char*)d_ws;
    int* flags = (int*)ws;                                  // 64 B
    int* gcur = (int*)(ws + 64);                            // 782*4 -> 3200 B
    int* scur = (int*)(ws + 3264);                          // 61*4  -> 244 B
    unsigned int* glist = (unsigned int*)(ws + 4160);       // 16.01 MB
    size_t glist_bytes = (size_t)NBK * CAP * 4;             // 16010240
    char* p = ws + 4160 + glist_bytes;
    // slist (13.75 MB) overlaps the post-binning buffers: dead after k_bin2.
    unsigned int* slist = (unsigned int*)p;                 // 61*56320*4 = 13.74 MB
    int* dstoff = (int*)p;                                  // 400 KB
    int* ddeg = (int*)(p + 400000);                         // 400 KB
    unsigned short* hbf = (unsigned short*)(p + 800000);    // 1.6 MB
    unsigned short* xs = (unsigned short*)(p + 2400000);    // 6.4 MB

    hipMemsetAsync(gcur, 0, 3456, stream);   // zeroes gcur + scur

    k_detect<<<1, 64, 0, stream>>>((const unsigned int*)x_u,
                                   (const unsigned int*)cand,
                                   (const unsigned int*)edges, flags);
    k_bin1<<<(NE + B1CH - 1) / B1CH, 256, 0, stream>>>(edges, scur, slist, flags);
    k_bin2<<<NSUP * SCH2, 256, 0, stream>>>(scur, slist, gcur, glist);
    k_sort<<<NBK, 256, 0, stream>>>(gcur, glist, dstoff, ddeg);
    k_gather1<<<(16 * NG + 255) / 256, 256, 0, stream>>>(dstoff, ddeg, glist, x_g,
                                                         W1r, W1o, b1, hbf, flags);
    k_gather2<<<(16 * NG + 255) / 256, 256, 0, stream>>>(dstoff, ddeg, glist,
                                                         (const ushortx8*)hbf,
                                                         W2r, W2o, b2, xs, flags);
    k_unconn<<<(NU + 255) / 256, 256, 0, stream>>>(x_u, Wun, bun, xs, flags);
    k_fc<<<1280, 256, 0, stream>>>(xs, cand, Wfc1, bfc1, Wfc2, bfc2, d_out, flags);
}

// Round 6
// 256.715 us; speedup vs baseline: 1.0933x; 1.0466x over previous
//
#include <hip/hip_runtime.h>
#include <hip/hip_bf16.h>

#define NG 100000
#define NU 100000
#define NE 3200000
#define NC 2000000

// dst-bucket binning: 128 dsts per bucket, SINGLE-LEVEL (R6: k_bin2 deleted;
// scattered 4B bucket writes are absorbed by L2 -- active write window is
// ~782 buckets x 64B = 50KB, trivially L2-resident)
#define BSZ 128
#define NBK 782          // ceil(NG/BSZ)
#define CAP 5120         // entries per fine bucket (mean 4096, +16 sigma)
#define B1CH 4096        // edges per bin1 block (LDS-staged single read)

typedef __attribute__((ext_vector_type(8))) short short8;
typedef __attribute__((ext_vector_type(4))) float floatx4;
typedef unsigned short ushortx8 __attribute__((ext_vector_type(8)));

// branchless SELU on the HW transcendental (6 VALU ops)
__device__ __forceinline__ float selu_f(float x) {
    const float LAM = 1.0507009873554805f;
    const float ALA = 1.7580993408473766f;  // LAM * ALPHA
    const float L2E = 1.44269504088896340736f;
    float e = __builtin_amdgcn_exp2f(fminf(x, 0.f) * L2E);
    return fmaf(LAM, fmaxf(x, 0.f), fmaf(ALA, e, -ALA));
}

__device__ __forceinline__ float bfbits2f(unsigned short u) {
    return __uint_as_float(((unsigned)u) << 16);
}

__device__ __forceinline__ unsigned short f2bfbits(float f) {
    union { __hip_bfloat16 h; unsigned short u; } cv;
    cv.h = __float2bfloat16(f);
    return cv.u;
}

__device__ __forceinline__ float ldf(const void* p, int i, int isbf) {
    return isbf ? bfbits2f(((const unsigned short*)p)[i]) : ((const float*)p)[i];
}

// ---- dtype detection: 64 lanes + ballot (was serial thread-0 loop) --------
__global__ void k_detect(const unsigned int* __restrict__ xw,
                         const unsigned int* __restrict__ cw,
                         const unsigned int* __restrict__ ew,
                         int* __restrict__ flags) {
    int lane = threadIdx.x;  // 64 threads
    unsigned lo = xw[lane] & 0xffffu;
    unsigned e = (lo >> 7) & 0xff;
    unsigned long long m1 = __ballot(e >= 112 && e <= 134);
    unsigned long long m2 = __ballot(cw[2 * lane + 1] == 0u);
    unsigned long long m3 = __ballot(ew[2 * lane + 1] == 0u);
    if (lane == 0) {
        flags[0] = (__popcll(m1) >= 32) ? 1 : 0;
        flags[1] = (__popcll(m2) >= 48) ? 1 : 0;
        flags[2] = (__popcll(m3) >= 48) ? 1 : 0;
    }
}

__device__ __forceinline__ void ld_edge(const void* edges, long long e, int e64,
                                        int& s, int& d) {
    if (e64) {
        const long long* el = (const long long*)edges;
        s = (int)el[e];
        d = (int)el[NE + e];
    } else {
        const int* ei = (const int*)edges;
        s = ei[e];
        d = ei[NE + e];
    }
}

// ---- Binning (single pass): edges -> 782 fine buckets directly.
//      Per block: LDS histogram over 782 bins (~5.2 entries/bin -> low
//      atomic contention), one global atomicAdd per non-empty bin, then
//      direct scattered write of the final payload (s<<7)|dl. No LDS
//      reorder: write coalescing is delegated to L2 (window ~50KB). -------
__global__ __launch_bounds__(256) void k_bin1(const void* __restrict__ edges,
        int* __restrict__ gcur, unsigned int* __restrict__ glist,
        const int* __restrict__ flags) {
    __shared__ unsigned int tmp[B1CH];         // 16 KB   payload (s<<7)|dl
    __shared__ unsigned short tfid[B1CH];      // 8 KB    fine bucket id
    __shared__ int hist[NBK];                  // 3.1 KB
    __shared__ int gbase[NBK];                 // 3.1 KB
    __shared__ int ofs[NBK];                   // 3.1 KB  -> ~33.4 KB, 4 blk/CU

    int tid = threadIdx.x;
    long long base = (long long)blockIdx.x * B1CH;
    int chunk = (int)(NE - base);
    if (chunk > B1CH) chunk = B1CH;
    int e64 = flags[2];

    for (int b = tid; b < NBK; b += 256) hist[b] = 0;
    __syncthreads();

    // phase A: single global read -> LDS stage + histogram
    for (int i = 0; i < B1CH / 256; ++i) {
        int idx = i * 256 + tid;
        if (idx < chunk) {
            int s, d;
            ld_edge(edges, base + idx, e64, s, d);
            int f = d >> 7;                       // BSZ = 128
            tmp[idx] = ((unsigned)s << 7) | (unsigned)(d & 127);
            tfid[idx] = (unsigned short)f;
            atomicAdd(&hist[f], 1);
        }
    }
    __syncthreads();

    // phase B: per-bucket global reservation
    for (int b = tid; b < NBK; b += 256) {
        int c = hist[b];
        gbase[b] = (c > 0) ? atomicAdd(&gcur[b], c) : 0;
        ofs[b] = 0;
    }
    __syncthreads();

    // phase C: direct scattered write-out (L2 absorbs; ~5 entries/bucket)
    for (int i = 0; i < B1CH / 256; ++i) {
        int idx = i * 256 + tid;
        if (idx < chunk) {
            int f = tfid[idx];
            int pos = atomicAdd(&ofs[f], 1);
            int p = gbase[f] + pos;
            if (p < CAP) glist[(long long)f * CAP + p] = tmp[idx];
        }
    }
}

// ---- Counting-sort each bucket by dl. SINGLE glist read (LDS-staged),
//      in-place write-back; emits per-dst CSR. R6: 2-wave shfl_up scan
//      (1 syncthreads) replaces the 14-sync Hillis-Steele. ----------------
__global__ __launch_bounds__(256) void k_sort(const int* __restrict__ gcur,
        unsigned int* __restrict__ glist,
        int* __restrict__ dstoff, int* __restrict__ ddeg) {
    __shared__ unsigned int tmp[CAP];      // 20 KB
    __shared__ unsigned int sorted[CAP];   // 20 KB
    __shared__ int hist[BSZ];
    __shared__ int cur[BSZ];
    __shared__ int wtot;
    int b = blockIdx.x;
    int tid = threadIdx.x;
    int cnt = gcur[b];
    if (cnt > CAP) cnt = CAP;
    unsigned int* lp = glist + (long long)b * CAP;

    if (tid < BSZ) hist[tid] = 0;
    __syncthreads();
    // single global read -> LDS + histogram
    for (int k = tid; k < cnt; k += 256) {
        unsigned u = lp[k];
        tmp[k] = u;
        atomicAdd(&hist[u & 127], 1);
    }
    __syncthreads();
    // inclusive scan of hist[0..127] across 2 waves via shfl_up
    int h = (tid < BSZ) ? hist[tid] : 0;
    int s = h;
#pragma unroll
    for (int off = 1; off < 64; off <<= 1) {
        int v = __shfl_up(s, off, 64);
        if ((tid & 63) >= off) s += v;
    }
    if (tid == 63) wtot = s;
    __syncthreads();
    if (tid >= 64 && tid < BSZ) s += wtot;
    if (tid < BSZ) {
        int excl = s - h;
        cur[tid] = excl;
        int d = b * BSZ + tid;
        if (d < NG) {
            dstoff[d] = b * CAP + excl;
            ddeg[d] = h;
        }
    }
    __syncthreads();
    for (int k = tid; k < cnt; k += 256) {
        unsigned u = tmp[k];
        int pos = atomicAdd(&cur[u & 127], 1);
        sorted[pos] = u >> 7;
    }
    __syncthreads();
    for (int k = tid; k < cnt; k += 256) lp[k] = sorted[k];
}

// ---- Gather+Node 1 fused: 16 threads/dst, paired independent gathers.
//      isbf hoisted out of the edge loop (wave-uniform). -------------------
__global__ __launch_bounds__(256) void k_gather1(const int* __restrict__ dstoff,
        const int* __restrict__ ddeg, const unsigned int* __restrict__ glist,
        const void* __restrict__ xg,
        const void* __restrict__ W1r, const void* __restrict__ W1o,
        const void* __restrict__ b1, unsigned short* __restrict__ hbf,
        const int* __restrict__ flags) {
    int gid = blockIdx.x * 256 + threadIdx.x;
    int d = gid >> 4;
    if (d >= NG) return;
    int q = gid & 15;
    int isbf = flags[0];
    int start = dstoff[d];
    int deg = ddeg[d];
    float a0 = 0.f, a1 = 0.f, a2 = 0.f, a3 = 0.f;
    if (isbf) {
        const unsigned short* xp = (const unsigned short*)xg;
        int k = q;
        for (; k + 16 < deg; k += 32) {
            int s0 = glist[start + k];
            int s1 = glist[start + k + 16];
            ushort4 r0 = *(const ushort4*)(xp + s0 * 4);
            ushort4 r1 = *(const ushort4*)(xp + s1 * 4);
            a0 += bfbits2f(r0.x) + bfbits2f(r1.x);
            a1 += bfbits2f(r0.y) + bfbits2f(r1.y);
            a2 += bfbits2f(r0.z) + bfbits2f(r1.z);
            a3 += bfbits2f(r0.w) + bfbits2f(r1.w);
        }
        for (; k < deg; k += 16) {
            int s = glist[start + k];
            ushort4 r = *(const ushort4*)(xp + s * 4);
            a0 += bfbits2f(r.x); a1 += bfbits2f(r.y);
            a2 += bfbits2f(r.z); a3 += bfbits2f(r.w);
        }
    } else {
        const float* xp = (const float*)xg;
        int k = q;
        for (; k + 16 < deg; k += 32) {
            int s0 = glist[start + k];
            int s1 = glist[start + k + 16];
            float4 r0 = *(const float4*)(xp + s0 * 4);
            float4 r1 = *(const float4*)(xp + s1 * 4);
            a0 += r0.x + r1.x;
            a1 += r0.y + r1.y;
            a2 += r0.z + r1.z;
            a3 += r0.w + r1.w;
        }
        for (; k < deg; k += 16) {
            int s = glist[start + k];
            float4 r = *(const float4*)(xp + s * 4);
            a0 += r.x; a1 += r.y; a2 += r.z; a3 += r.w;
        }
    }
#pragma unroll
    for (int off = 1; off < 16; off <<= 1) {
        a0 += __shfl_xor(a0, off);
        a1 += __shfl_xor(a1, off);
        a2 += __shfl_xor(a2, off);
        a3 += __shfl_xor(a3, off);
    }
    if (q < 8) {
        float a[4] = {a0, a1, a2, a3};
        float v = ldf(b1, q, isbf);
#pragma unroll
        for (int c = 0; c < 4; ++c)
            v += a[c] * ldf(W1r, c * 8 + q, isbf)
               + ldf(xg, d * 4 + c, isbf) * ldf(W1o, c * 8 + q, isbf);
        hbf[d * 8 + q] = f2bfbits(selu_f(v));
    }
}

// ---- Gather+Node 2 fused: 16 threads/dst; lane q -> output j=q ------------
__global__ __launch_bounds__(256) void k_gather2(const int* __restrict__ dstoff,
        const int* __restrict__ ddeg, const unsigned int* __restrict__ glist,
        const ushortx8* __restrict__ hbf,
        const void* __restrict__ W2r, const void* __restrict__ W2o,
        const void* __restrict__ b2, unsigned short* __restrict__ xs,
        const int* __restrict__ flags) {
    int gid = blockIdx.x * 256 + threadIdx.x;
    int d = gid >> 4;
    if (d >= NG) return;
    int q = gid & 15;
    int isbf = flags[0];
    int start = dstoff[d];
    int deg = ddeg[d];
    float a[8] = {0.f, 0.f, 0.f, 0.f, 0.f, 0.f, 0.f, 0.f};
    int k = q;
    for (; k + 16 < deg; k += 32) {
        int s0 = glist[start + k];
        int s1 = glist[start + k + 16];
        ushortx8 r0 = hbf[s0];
        ushortx8 r1 = hbf[s1];
#pragma unroll
        for (int c = 0; c < 8; ++c)
            a[c] += bfbits2f((unsigned short)r0[c]) + bfbits2f((unsigned short)r1[c]);
    }
    for (; k < deg; k += 16) {
        int s = glist[start + k];
        ushortx8 r = hbf[s];
#pragma unroll
        for (int c = 0; c < 8; ++c) a[c] += bfbits2f((unsigned short)r[c]);
    }
#pragma unroll
    for (int off = 1; off < 16; off <<= 1) {
#pragma unroll
        for (int c = 0; c < 8; ++c) a[c] += __shfl_xor(a[c], off);
    }
    ushortx8 hr = hbf[d];
    float hv[8];
#pragma unroll
    for (int c = 0; c < 8; ++c) hv[c] = bfbits2f((unsigned short)hr[c]);
    float v = ldf(b2, q, isbf);
#pragma unroll
    for (int c = 0; c < 8; ++c)
        v += a[c] * ldf(W2r, c * 16 + q, isbf)
           + hv[c] * ldf(W2o, c * 16 + q, isbf);
    xs[d * 16 + q] = f2bfbits(selu_f(v));
}

// ---- fc_unconnected -> x_stacked[NG:NG+NU] (bf16), NO selu ----------------
__global__ __launch_bounds__(256) void k_unconn(const void* __restrict__ xu,
        const void* __restrict__ Wun, const void* __restrict__ bun,
        unsigned short* __restrict__ xs, const int* __restrict__ flags) {
    int u = blockIdx.x * 256 + threadIdx.x;
    if (u >= NU) return;
    int isbf = flags[0];
    float x[4];
#pragma unroll
    for (int k = 0; k < 4; ++k) x[k] = ldf(xu, u * 4 + k, isbf);
    ushortx8 lo, hi;
#pragma unroll
    for (int j = 0; j < 16; ++j) {
        float v = ldf(bun, j, isbf);
#pragma unroll
        for (int k = 0; k < 4; ++k)
            v += x[k] * ldf(Wun, k * 16 + j, isbf);
        unsigned short bb = f2bfbits(v);
        if (j < 8) lo[j] = bb; else hi[j - 8] = bb;
    }
    ushortx8* xp = (ushortx8*)(xs + (NG + u) * 16);
    xp[0] = lo;
    xp[1] = hi;
}

// per-lane candidate ROW index: lane half-group hp=half>>1 selects endpoint.
// c64: low 32 bits of int64 little-endian at int-index 2*(2c+hp).
__device__ __forceinline__ int ld_candrow(const void* cand, int c, int hp, int c64) {
    const int* ci = (const int*)cand;
    return c64 ? ci[(2 * c + hp) * 2] : ci[2 * c + hp];
}

// ---- FC head: persistent waves, 4-deep software-pipelined gather.
//      (unchanged from R5; memory-latency-bound on the scattered xs gather,
//      parked at ~50us -- further MLP gave diminishing returns.) -----------
__global__ __launch_bounds__(256, 5) void k_fc(const unsigned short* __restrict__ xs,
        const void* __restrict__ cand,
        const void* __restrict__ Wfc1, const void* __restrict__ bfc1,
        const void* __restrict__ Wfc2, const void* __restrict__ bfc2,
        void* __restrict__ out, const int* __restrict__ flags) {
    const float LAM = 1.0507009873554805f;
    const float ALA = 1.7580993408473766f;  // LAM * ALPHA
    const float L2E = 1.44269504088896340736f;
    const float AR2 = 1.6732632423543772f * 1.44269504088896340736f;  // ALPHA*L2E
    const float SCL = 1.0507009873554805f / 1.44269504088896340736f;  // LAM/L2E
    int lane = threadIdx.x & 63;
    int wid = (blockIdx.x * blockDim.x + threadIdx.x) >> 6;
    int m = lane & 15;
    int half = lane >> 4;
    int isbf = flags[0], c64 = flags[1];

    short8 wfrag[4];
    floatx4 cbias[4];
    float w2s[4][4];
    float c_corr;
    if (isbf) {
        const unsigned short* W1p = (const unsigned short*)Wfc1;
#pragma unroll
        for (int t = 0; t < 4; ++t)
#pragma unroll
            for (int j = 0; j < 8; ++j)
                wfrag[t][j] = (short)f2bfbits(
                    bfbits2f(W1p[(half * 8 + j) * 64 + t * 16 + m]) * L2E);
        const unsigned short* b1p = (const unsigned short*)bfc1;
        const unsigned short* w2p = (const unsigned short*)Wfc2;
        float asum = 0.f;
#pragma unroll
        for (int t = 0; t < 4; ++t)
#pragma unroll
            for (int r = 0; r < 4; ++r) {
                int h = t * 16 + half * 4 + r;
                cbias[t][r] = bfbits2f(b1p[h]) * L2E;
                float w2 = bfbits2f(w2p[h]);
                w2s[t][r] = w2 * SCL;
                asum += w2 * ALA;
            }
        asum += __shfl_xor(asum, 16, 64);
        asum += __shfl_xor(asum, 32, 64);
        c_corr = bfbits2f(((const unsigned short*)bfc2)[0]) - asum;
    } else {
        const float* W1p = (const float*)Wfc1;
#pragma unroll
        for (int t = 0; t < 4; ++t)
#pragma unroll
            for (int j = 0; j < 8; ++j)
                wfrag[t][j] = (short)f2bfbits(
                    W1p[(half * 8 + j) * 64 + t * 16 + m] * L2E);
        const float* b1p = (const float*)bfc1;
        const float* w2p = (const float*)Wfc2;
        float asum = 0.f;
#pragma unroll
        for (int t = 0; t < 4; ++t)
#pragma unroll
            for (int r = 0; r < 4; ++r) {
                int h = t * 16 + half * 4 + r;
                cbias[t][r] = b1p[h] * L2E;
                float w2 = w2p[h];
                w2s[t][r] = w2 * SCL;
                asum += w2 * ALA;
            }
        asum += __shfl_xor(asum, 16, 64);
        asum += __shfl_xor(asum, 32, 64);
        c_corr = ((const float*)bfc2)[0] - asum;
    }

    const int nTiles = NC / 16;
    int nW = (gridDim.x * blockDim.x) >> 6;
    if (wid >= nTiles) return;

    int half1 = half & 1;
    int hp = half >> 1;
    // 4-deep gather pipeline: af for tiles t..t+3nW in flight; row-index
    // queue one tile further ahead.
    int t1 = wid + nW, t2 = wid + 2 * nW, t3 = wid + 3 * nW, t4 = wid + 4 * nW;
    int r0i = ld_candrow(cand, wid * 16 + m, hp, c64);
    int r1i = ld_candrow(cand, ((t1 < nTiles) ? t1 : wid) * 16 + m, hp, c64);
    int r2i = ld_candrow(cand, ((t2 < nTiles) ? t2 : wid) * 16 + m, hp, c64);
    int r3i = ld_candrow(cand, ((t3 < nTiles) ? t3 : wid) * 16 + m, hp, c64);
    int r4i = ld_candrow(cand, ((t4 < nTiles) ? t4 : wid) * 16 + m, hp, c64);
    {
        short8 af0 = *(const short8*)(xs + r0i * 16 + half1 * 8);
        short8 af1 = *(const short8*)(xs + r1i * 16 + half1 * 8);
        short8 af2 = *(const short8*)(xs + r2i * 16 + half1 * 8);
        short8 af3 = *(const short8*)(xs + r3i * 16 + half1 * 8);

#pragma unroll 2
        for (int t = wid; t < nTiles; t += nW) {
            int tn5 = t + 5 * nW;
            int r5i = ld_candrow(cand, ((tn5 < nTiles) ? tn5 : t) * 16 + m, hp, c64);
            short8 af4 = *(const short8*)(xs + r4i * 16 + half1 * 8);

            float ps[4];
#pragma unroll
            for (int tt = 0; tt < 4; ++tt) {
                floatx4 ac = __builtin_amdgcn_mfma_f32_16x16x32_bf16(
                    wfrag[tt], af0, cbias[tt], 0, 0, 0);
                float s = 0.f;
#pragma unroll
                for (int r = 0; r < 4; ++r) {
                    float v = ac[r];
                    float mx = fmaxf(v, 0.f);
                    float e = __builtin_amdgcn_exp2f(fminf(v, 0.f));
                    s = fmaf(w2s[tt][r], fmaf(AR2, e, mx), s);
                }
                ps[tt] = s;
            }
            float part = (ps[0] + ps[1]) + (ps[2] + ps[3]);
            part += __shfl_xor(part, 16, 64);
            part += __shfl_xor(part, 32, 64);
            if (half == 0) {
                float o = part + c_corr;
                if (isbf) ((unsigned short*)out)[t * 16 + m] = f2bfbits(o);
                else ((float*)out)[t * 16 + m] = o;
            }
            af0 = af1;
            af1 = af2;
            af2 = af3;
            af3 = af4;
            r4i = r5i;
        }
    }
}

extern "C" void kernel_launch(void* const* d_in, const int* in_sizes, int n_in,
                              void* d_out, int out_size, void* d_ws, size_t ws_size,
                              hipStream_t stream) {
    const void* x_u = d_in[0];
    const void* x_g = d_in[1];
    const void* cand = d_in[2];
    const void* edges = d_in[3];
    const void* W1r = d_in[4];
    const void* W1o = d_in[5];
    const void* b1 = d_in[6];
    const void* W2r = d_in[7];
    const void* W2o = d_in[8];
    const void* b2 = d_in[9];
    const void* Wun = d_in[10];
    const void* bun = d_in[11];
    const void* Wfc1 = d_in[12];
    const void* bfc1 = d_in[13];
    const void* Wfc2 = d_in[14];
    const void* bfc2 = d_in[15];

    char* ws = (char*)d_ws;
    int* flags = (int*)ws;                                  // 64 B
    int* gcur = (int*)(ws + 64);                            // 782*4 -> 3200 B
    unsigned int* glist = (unsigned int*)(ws + 4160);       // 16.01 MB
    size_t glist_bytes = (size_t)NBK * CAP * 4;             // 16010240
    char* p = ws + 4160 + glist_bytes;
    int* dstoff = (int*)p;                                  // 400 KB
    int* ddeg = (int*)(p + 400000);                         // 400 KB
    unsigned short* hbf = (unsigned short*)(p + 800000);    // 1.6 MB
    unsigned short* xs = (unsigned short*)(p + 2400000);    // 6.4 MB

    hipMemsetAsync(gcur, 0, 3200, stream);

    k_detect<<<1, 64, 0, stream>>>((const unsigned int*)x_u,
                                   (const unsigned int*)cand,
                                   (const unsigned int*)edges, flags);
    k_bin1<<<(NE + B1CH - 1) / B1CH, 256, 0, stream>>>(edges, gcur, glist, flags);
    k_sort<<<NBK, 256, 0, stream>>>(gcur, glist, dstoff, ddeg);
    k_gather1<<<(16 * NG + 255) / 256, 256, 0, stream>>>(dstoff, ddeg, glist, x_g,
                                                         W1r, W1o, b1, hbf, flags);
    k_gather2<<<(16 * NG + 255) / 256, 256, 0, stream>>>(dstoff, ddeg, glist,
                                                         (const ushortx8*)hbf,
                                                         W2r, W2o, b2, xs, flags);
    k_unconn<<<(NU + 255) / 256, 256, 0, stream>>>(x_u, Wun, bun, xs, flags);
    k_fc<<<1280, 256, 0, stream>>>(xs, cand, Wfc1, bfc1, Wfc2, bfc2, d_out, flags);
}

// Round 7
// 256.050 us; speedup vs baseline: 1.0962x; 1.0026x over previous
//
#include <hip/hip_runtime.h>
#include <hip/hip_bf16.h>

#define NG 100000
#define NU 100000
#define NE 3200000
#define NC 2000000

// dst-bucket binning: 128 dsts per bucket, SINGLE-LEVEL (R6: k_bin2 deleted;
// scattered 4B bucket writes are absorbed by L2)
#define BSZ 128
#define NBK 782          // ceil(NG/BSZ)
#define CAP 5120         // entries per fine bucket (mean 4096, +16 sigma)
#define B1CH 4096        // edges per bin1 block (LDS-staged single read)

typedef __attribute__((ext_vector_type(8))) short short8;
typedef __attribute__((ext_vector_type(4))) float floatx4;
typedef unsigned short ushortx8 __attribute__((ext_vector_type(8)));

// branchless SELU on the HW transcendental (6 VALU ops)
__device__ __forceinline__ float selu_f(float x) {
    const float LAM = 1.0507009873554805f;
    const float ALA = 1.7580993408473766f;  // LAM * ALPHA
    const float L2E = 1.44269504088896340736f;
    float e = __builtin_amdgcn_exp2f(fminf(x, 0.f) * L2E);
    return fmaf(LAM, fmaxf(x, 0.f), fmaf(ALA, e, -ALA));
}

__device__ __forceinline__ float bfbits2f(unsigned short u) {
    return __uint_as_float(((unsigned)u) << 16);
}

__device__ __forceinline__ unsigned short f2bfbits(float f) {
    union { __hip_bfloat16 h; unsigned short u; } cv;
    cv.h = __float2bfloat16(f);
    return cv.u;
}

__device__ __forceinline__ float ldf(const void* p, int i, int isbf) {
    return isbf ? bfbits2f(((const unsigned short*)p)[i]) : ((const float*)p)[i];
}

__device__ __forceinline__ void ld_edge(const void* edges, long long e, int e64,
                                        int& s, int& d) {
    if (e64) {
        const long long* el = (const long long*)edges;
        s = (int)el[e];
        d = (int)el[NE + e];
    } else {
        const int* ei = (const int*)edges;
        s = ei[e];
        d = ei[NE + e];
    }
}

// ---- Binning (single pass): edges -> 782 fine buckets directly.
//      R7: self-detects e64 (wave-0 ballot on the edge words) -- the
//      separate k_detect launch is deleted (in-order stream => it was pure
//      serial prefix). -----------------------------------------------------
__global__ __launch_bounds__(256) void k_bin1(const void* __restrict__ edges,
        int* __restrict__ gcur, unsigned int* __restrict__ glist) {
    __shared__ unsigned int tmp[B1CH];         // 16 KB   payload (s<<7)|dl
    __shared__ unsigned short tfid[B1CH];      // 8 KB    fine bucket id
    __shared__ int hist[NBK];                  // 3.1 KB
    __shared__ int gbase[NBK];                 // 3.1 KB
    __shared__ int ofs[NBK];                   // 3.1 KB  -> ~33.4 KB, 4 blk/CU
    __shared__ int se64;

    int tid = threadIdx.x;
    long long base = (long long)blockIdx.x * B1CH;
    int chunk = (int)(NE - base);
    if (chunk > B1CH) chunk = B1CH;

    // self-detect int64 vs int32 edges (wave 0; same rule as old k_detect)
    if (tid < 64) {
        unsigned long long m3 =
            __ballot(((const unsigned int*)edges)[2 * tid + 1] == 0u);
        if (tid == 0) se64 = (__popcll(m3) >= 48) ? 1 : 0;
    }
    for (int b = tid; b < NBK; b += 256) hist[b] = 0;
    __syncthreads();
    int e64 = se64;

    // phase A: single global read -> LDS stage + histogram
    for (int i = 0; i < B1CH / 256; ++i) {
        int idx = i * 256 + tid;
        if (idx < chunk) {
            int s, d;
            ld_edge(edges, base + idx, e64, s, d);
            int f = d >> 7;                       // BSZ = 128
            tmp[idx] = ((unsigned)s << 7) | (unsigned)(d & 127);
            tfid[idx] = (unsigned short)f;
            atomicAdd(&hist[f], 1);
        }
    }
    __syncthreads();

    // phase B: per-bucket global reservation
    for (int b = tid; b < NBK; b += 256) {
        int c = hist[b];
        gbase[b] = (c > 0) ? atomicAdd(&gcur[b], c) : 0;
        ofs[b] = 0;
    }
    __syncthreads();

    // phase C: direct scattered write-out (L2 absorbs)
    for (int i = 0; i < B1CH / 256; ++i) {
        int idx = i * 256 + tid;
        if (idx < chunk) {
            int f = tfid[idx];
            int pos = atomicAdd(&ofs[f], 1);
            int p = gbase[f] + pos;
            if (p < CAP) glist[(long long)f * CAP + p] = tmp[idx];
        }
    }
}

// ---- Counting-sort each bucket by dl. R7: direct scattered final write
//      (bucket-local, L2-absorbed) replaces the `sorted` LDS staging +
//      copy-back: LDS 41.5 -> ~21.3 KB => 3 -> 7 blocks/CU (782-block grid
//      is a single residency round, so block latency == kernel time).
//      In-place safe: all glist reads drain before the first barrier.
//      Block 0 wave 0 also computes the dtype flags (k_detect deleted);
//      flags are consumed first by k_gather1, which launches later. -------
__global__ __launch_bounds__(256) void k_sort(const int* __restrict__ gcur,
        unsigned int* __restrict__ glist,
        int* __restrict__ dstoff, int* __restrict__ ddeg,
        const unsigned int* __restrict__ xw, const unsigned int* __restrict__ cw,
        const unsigned int* __restrict__ ew, int* __restrict__ flags) {
    __shared__ unsigned int tmp[CAP];      // 20 KB
    __shared__ int hist[BSZ];
    __shared__ int cur[BSZ];
    __shared__ int wtot;                   // ~21.3 KB -> 7 blocks/CU
    int b = blockIdx.x;
    int tid = threadIdx.x;

    if (b == 0 && tid < 64) {
        unsigned lo = xw[tid] & 0xffffu;
        unsigned e = (lo >> 7) & 0xff;
        unsigned long long m1 = __ballot(e >= 112 && e <= 134);
        unsigned long long m2 = __ballot(cw[2 * tid + 1] == 0u);
        unsigned long long m3 = __ballot(ew[2 * tid + 1] == 0u);
        if (tid == 0) {
            flags[0] = (__popcll(m1) >= 32) ? 1 : 0;
            flags[1] = (__popcll(m2) >= 48) ? 1 : 0;
            flags[2] = (__popcll(m3) >= 48) ? 1 : 0;
        }
    }

    int cnt = gcur[b];
    if (cnt > CAP) cnt = CAP;
    unsigned int* lp = glist + (long long)b * CAP;

    if (tid < BSZ) hist[tid] = 0;
    __syncthreads();
    // single global read -> LDS + histogram
    for (int k = tid; k < cnt; k += 256) {
        unsigned u = lp[k];
        tmp[k] = u;
        atomicAdd(&hist[u & 127], 1);
    }
    __syncthreads();
    // inclusive scan of hist[0..127] across 2 waves via shfl_up
    int h = (tid < BSZ) ? hist[tid] : 0;
    int s = h;
#pragma unroll
    for (int off = 1; off < 64; off <<= 1) {
        int v = __shfl_up(s, off, 64);
        if ((tid & 63) >= off) s += v;
    }
    if (tid == 63) wtot = s;
    __syncthreads();
    if (tid >= 64 && tid < BSZ) s += wtot;
    if (tid < BSZ) {
        int excl = s - h;
        cur[tid] = excl;
        int d = b * BSZ + tid;
        if (d < NG) {
            dstoff[d] = b * CAP + excl;
            ddeg[d] = h;
        }
    }
    __syncthreads();
    // direct scattered final write (reads of lp fully drained pre-barrier)
    for (int k = tid; k < cnt; k += 256) {
        unsigned u = tmp[k];
        int pos = atomicAdd(&cur[u & 127], 1);
        lp[pos] = u >> 7;
    }
}

// ---- Gather+Node 1 fused: 16 threads/dst, paired independent gathers.
//      isbf hoisted out of the edge loop (wave-uniform). -------------------
__global__ __launch_bounds__(256) void k_gather1(const int* __restrict__ dstoff,
        const int* __restrict__ ddeg, const unsigned int* __restrict__ glist,
        const void* __restrict__ xg,
        const void* __restrict__ W1r, const void* __restrict__ W1o,
        const void* __restrict__ b1, unsigned short* __restrict__ hbf,
        const int* __restrict__ flags) {
    int gid = blockIdx.x * 256 + threadIdx.x;
    int d = gid >> 4;
    if (d >= NG) return;
    int q = gid & 15;
    int isbf = flags[0];
    int start = dstoff[d];
    int deg = ddeg[d];
    float a0 = 0.f, a1 = 0.f, a2 = 0.f, a3 = 0.f;
    if (isbf) {
        const unsigned short* xp = (const unsigned short*)xg;
        int k = q;
        for (; k + 16 < deg; k += 32) {
            int s0 = glist[start + k];
            int s1 = glist[start + k + 16];
            ushort4 r0 = *(const ushort4*)(xp + s0 * 4);
            ushort4 r1 = *(const ushort4*)(xp + s1 * 4);
            a0 += bfbits2f(r0.x) + bfbits2f(r1.x);
            a1 += bfbits2f(r0.y) + bfbits2f(r1.y);
            a2 += bfbits2f(r0.z) + bfbits2f(r1.z);
            a3 += bfbits2f(r0.w) + bfbits2f(r1.w);
        }
        for (; k < deg; k += 16) {
            int s = glist[start + k];
            ushort4 r = *(const ushort4*)(xp + s * 4);
            a0 += bfbits2f(r.x); a1 += bfbits2f(r.y);
            a2 += bfbits2f(r.z); a3 += bfbits2f(r.w);
        }
    } else {
        const float* xp = (const float*)xg;
        int k = q;
        for (; k + 16 < deg; k += 32) {
            int s0 = glist[start + k];
            int s1 = glist[start + k + 16];
            float4 r0 = *(const float4*)(xp + s0 * 4);
            float4 r1 = *(const float4*)(xp + s1 * 4);
            a0 += r0.x + r1.x;
            a1 += r0.y + r1.y;
            a2 += r0.z + r1.z;
            a3 += r0.w + r1.w;
        }
        for (; k < deg; k += 16) {
            int s = glist[start + k];
            float4 r = *(const float4*)(xp + s * 4);
            a0 += r.x; a1 += r.y; a2 += r.z; a3 += r.w;
        }
    }
#pragma unroll
    for (int off = 1; off < 16; off <<= 1) {
        a0 += __shfl_xor(a0, off);
        a1 += __shfl_xor(a1, off);
        a2 += __shfl_xor(a2, off);
        a3 += __shfl_xor(a3, off);
    }
    if (q < 8) {
        float a[4] = {a0, a1, a2, a3};
        float v = ldf(b1, q, isbf);
#pragma unroll
        for (int c = 0; c < 4; ++c)
            v += a[c] * ldf(W1r, c * 8 + q, isbf)
               + ldf(xg, d * 4 + c, isbf) * ldf(W1o, c * 8 + q, isbf);
        hbf[d * 8 + q] = f2bfbits(selu_f(v));
    }
}

#define G2BLK ((16 * NG + 255) / 256)   // 6250 gather2 blocks
#define UCBLK ((NU + 255) / 256)        // 391 unconn blocks

// ---- Gather+Node 2 fused + fc_unconnected (R7: unconn runs as extra grid
//      blocks -- one launch fewer; both paths wave-uniform). ---------------
__global__ __launch_bounds__(256) void k_gather2(const int* __restrict__ dstoff,
        const int* __restrict__ ddeg, const unsigned int* __restrict__ glist,
        const ushortx8* __restrict__ hbf,
        const void* __restrict__ W2r, const void* __restrict__ W2o,
        const void* __restrict__ b2, unsigned short* __restrict__ xs,
        const void* __restrict__ xu, const void* __restrict__ Wun,
        const void* __restrict__ bun, const int* __restrict__ flags) {
    int isbf = flags[0];
    if (blockIdx.x >= G2BLK) {
        // ---- unconn path: x_u @ W_un + b_un -> xs[NG:], no selu ----
        int u = (blockIdx.x - G2BLK) * 256 + threadIdx.x;
        if (u >= NU) return;
        float x[4];
#pragma unroll
        for (int k = 0; k < 4; ++k) x[k] = ldf(xu, u * 4 + k, isbf);
        ushortx8 lo, hi;
#pragma unroll
        for (int j = 0; j < 16; ++j) {
            float v = ldf(bun, j, isbf);
#pragma unroll
            for (int k = 0; k < 4; ++k)
                v += x[k] * ldf(Wun, k * 16 + j, isbf);
            unsigned short bb = f2bfbits(v);
            if (j < 8) lo[j] = bb; else hi[j - 8] = bb;
        }
        ushortx8* xp = (ushortx8*)(xs + (NG + u) * 16);
        xp[0] = lo;
        xp[1] = hi;
        return;
    }
    int gid = blockIdx.x * 256 + threadIdx.x;
    int d = gid >> 4;
    if (d >= NG) return;
    int q = gid & 15;
    int start = dstoff[d];
    int deg = ddeg[d];
    float a[8] = {0.f, 0.f, 0.f, 0.f, 0.f, 0.f, 0.f, 0.f};
    int k = q;
    for (; k + 16 < deg; k += 32) {
        int s0 = glist[start + k];
        int s1 = glist[start + k + 16];
        ushortx8 r0 = hbf[s0];
        ushortx8 r1 = hbf[s1];
#pragma unroll
        for (int c = 0; c < 8; ++c)
            a[c] += bfbits2f((unsigned short)r0[c]) + bfbits2f((unsigned short)r1[c]);
    }
    for (; k < deg; k += 16) {
        int s = glist[start + k];
        ushortx8 r = hbf[s];
#pragma unroll
        for (int c = 0; c < 8; ++c) a[c] += bfbits2f((unsigned short)r[c]);
    }
#pragma unroll
    for (int off = 1; off < 16; off <<= 1) {
#pragma unroll
        for (int c = 0; c < 8; ++c) a[c] += __shfl_xor(a[c], off);
    }
    ushortx8 hr = hbf[d];
    float hv[8];
#pragma unroll
    for (int c = 0; c < 8; ++c) hv[c] = bfbits2f((unsigned short)hr[c]);
    float v = ldf(b2, q, isbf);
#pragma unroll
    for (int c = 0; c < 8; ++c)
        v += a[c] * ldf(W2r, c * 16 + q, isbf)
           + hv[c] * ldf(W2o, c * 16 + q, isbf);
    xs[d * 16 + q] = f2bfbits(selu_f(v));
}

// per-lane candidate ROW index: lane half-group hp=half>>1 selects endpoint.
// c64: low 32 bits of int64 little-endian at int-index 2*(2c+hp).
__device__ __forceinline__ int ld_candrow(const void* cand, int c, int hp, int c64) {
    const int* ci = (const int*)cand;
    return c64 ? ci[(2 * c + hp) * 2] : ci[2 * c + hp];
}

// ---- FC head: persistent waves, 4-deep software-pipelined gather.
//      (frozen since R5: memory-latency-bound on the scattered xs gather;
//      serves as the measurement anchor in the top-5.) ---------------------
__global__ __launch_bounds__(256, 5) void k_fc(const unsigned short* __restrict__ xs,
        const void* __restrict__ cand,
        const void* __restrict__ Wfc1, const void* __restrict__ bfc1,
        const void* __restrict__ Wfc2, const void* __restrict__ bfc2,
        void* __restrict__ out, const int* __restrict__ flags) {
    const float LAM = 1.0507009873554805f;
    const float ALA = 1.7580993408473766f;  // LAM * ALPHA
    const float L2E = 1.44269504088896340736f;
    const float AR2 = 1.6732632423543772f * 1.44269504088896340736f;  // ALPHA*L2E
    const float SCL = 1.0507009873554805f / 1.44269504088896340736f;  // LAM/L2E
    int lane = threadIdx.x & 63;
    int wid = (blockIdx.x * blockDim.x + threadIdx.x) >> 6;
    int m = lane & 15;
    int half = lane >> 4;
    int isbf = flags[0], c64 = flags[1];

    short8 wfrag[4];
    floatx4 cbias[4];
    float w2s[4][4];
    float c_corr;
    if (isbf) {
        const unsigned short* W1p = (const unsigned short*)Wfc1;
#pragma unroll
        for (int t = 0; t < 4; ++t)
#pragma unroll
            for (int j = 0; j < 8; ++j)
                wfrag[t][j] = (short)f2bfbits(
                    bfbits2f(W1p[(half * 8 + j) * 64 + t * 16 + m]) * L2E);
        const unsigned short* b1p = (const unsigned short*)bfc1;
        const unsigned short* w2p = (const unsigned short*)Wfc2;
        float asum = 0.f;
#pragma unroll
        for (int t = 0; t < 4; ++t)
#pragma unroll
            for (int r = 0; r < 4; ++r) {
                int h = t * 16 + half * 4 + r;
                cbias[t][r] = bfbits2f(b1p[h]) * L2E;
                float w2 = bfbits2f(w2p[h]);
                w2s[t][r] = w2 * SCL;
                asum += w2 * ALA;
            }
        asum += __shfl_xor(asum, 16, 64);
        asum += __shfl_xor(asum, 32, 64);
        c_corr = bfbits2f(((const unsigned short*)bfc2)[0]) - asum;
    } else {
        const float* W1p = (const float*)Wfc1;
#pragma unroll
        for (int t = 0; t < 4; ++t)
#pragma unroll
            for (int j = 0; j < 8; ++j)
                wfrag[t][j] = (short)f2bfbits(
                    W1p[(half * 8 + j) * 64 + t * 16 + m] * L2E);
        const float* b1p = (const float*)bfc1;
        const float* w2p = (const float*)Wfc2;
        float asum = 0.f;
#pragma unroll
        for (int t = 0; t < 4; ++t)
#pragma unroll
            for (int r = 0; r < 4; ++r) {
                int h = t * 16 + half * 4 + r;
                cbias[t][r] = b1p[h] * L2E;
                float w2 = w2p[h];
                w2s[t][r] = w2 * SCL;
                asum += w2 * ALA;
            }
        asum += __shfl_xor(asum, 16, 64);
        asum += __shfl_xor(asum, 32, 64);
        c_corr = ((const float*)bfc2)[0] - asum;
    }

    const int nTiles = NC / 16;
    int nW = (gridDim.x * blockDim.x) >> 6;
    if (wid >= nTiles) return;

    int half1 = half & 1;
    int hp = half >> 1;
    // 4-deep gather pipeline: af for tiles t..t+3nW in flight; row-index
    // queue one tile further ahead.
    int t1 = wid + nW, t2 = wid + 2 * nW, t3 = wid + 3 * nW, t4 = wid + 4 * nW;
    int r0i = ld_candrow(cand, wid * 16 + m, hp, c64);
    int r1i = ld_candrow(cand, ((t1 < nTiles) ? t1 : wid) * 16 + m, hp, c64);
    int r2i = ld_candrow(cand, ((t2 < nTiles) ? t2 : wid) * 16 + m, hp, c64);
    int r3i = ld_candrow(cand, ((t3 < nTiles) ? t3 : wid) * 16 + m, hp, c64);
    int r4i = ld_candrow(cand, ((t4 < nTiles) ? t4 : wid) * 16 + m, hp, c64);
    {
        short8 af0 = *(const short8*)(xs + r0i * 16 + half1 * 8);
        short8 af1 = *(const short8*)(xs + r1i * 16 + half1 * 8);
        short8 af2 = *(const short8*)(xs + r2i * 16 + half1 * 8);
        short8 af3 = *(const short8*)(xs + r3i * 16 + half1 * 8);

#pragma unroll 2
        for (int t = wid; t < nTiles; t += nW) {
            int tn5 = t + 5 * nW;
            int r5i = ld_candrow(cand, ((tn5 < nTiles) ? tn5 : t) * 16 + m, hp, c64);
            short8 af4 = *(const short8*)(xs + r4i * 16 + half1 * 8);

            float ps[4];
#pragma unroll
            for (int tt = 0; tt < 4; ++tt) {
                floatx4 ac = __builtin_amdgcn_mfma_f32_16x16x32_bf16(
                    wfrag[tt], af0, cbias[tt], 0, 0, 0);
                float s = 0.f;
#pragma unroll
                for (int r = 0; r < 4; ++r) {
                    float v = ac[r];
                    float mx = fmaxf(v, 0.f);
                    float e = __builtin_amdgcn_exp2f(fminf(v, 0.f));
                    s = fmaf(w2s[tt][r], fmaf(AR2, e, mx), s);
                }
                ps[tt] = s;
            }
            float part = (ps[0] + ps[1]) + (ps[2] + ps[3]);
            part += __shfl_xor(part, 16, 64);
            part += __shfl_xor(part, 32, 64);
            if (half == 0) {
                float o = part + c_corr;
                if (isbf) ((unsigned short*)out)[t * 16 + m] = f2bfbits(o);
                else ((float*)out)[t * 16 + m] = o;
            }
            af0 = af1;
            af1 = af2;
            af2 = af3;
            af3 = af4;
            r4i = r5i;
        }
    }
}

extern "C" void kernel_launch(void* const* d_in, const int* in_sizes, int n_in,
                              void* d_out, int out_size, void* d_ws, size_t ws_size,
                              hipStream_t stream) {
    const void* x_u = d_in[0];
    const void* x_g = d_in[1];
    const void* cand = d_in[2];
    const void* edges = d_in[3];
    const void* W1r = d_in[4];
    const void* W1o = d_in[5];
    const void* b1 = d_in[6];
    const void* W2r = d_in[7];
    const void* W2o = d_in[8];
    const void* b2 = d_in[9];
    const void* Wun = d_in[10];
    const void* bun = d_in[11];
    const void* Wfc1 = d_in[12];
    const void* bfc1 = d_in[13];
    const void* Wfc2 = d_in[14];
    const void* bfc2 = d_in[15];

    char* ws = (char*)d_ws;
    int* flags = (int*)ws;                                  // 64 B
    int* gcur = (int*)(ws + 64);                            // 782*4 -> 3200 B
    unsigned int* glist = (unsigned int*)(ws + 4160);       // 16.01 MB
    size_t glist_bytes = (size_t)NBK * CAP * 4;             // 16010240
    char* p = ws + 4160 + glist_bytes;
    int* dstoff = (int*)p;                                  // 400 KB
    int* ddeg = (int*)(p + 400000);                         // 400 KB
    unsigned short* hbf = (unsigned short*)(p + 800000);    // 1.6 MB
    unsigned short* xs = (unsigned short*)(p + 2400000);    // 6.4 MB

    hipMemsetAsync(gcur, 0, 3200, stream);

    k_bin1<<<(NE + B1CH - 1) / B1CH, 256, 0, stream>>>(edges, gcur, glist);
    k_sort<<<NBK, 256, 0, stream>>>(gcur, glist, dstoff, ddeg,
                                    (const unsigned int*)x_u,
                                    (const unsigned int*)cand,
                                    (const unsigned int*)edges, flags);
    k_gather1<<<(16 * NG + 255) / 256, 256, 0, stream>>>(dstoff, ddeg, glist, x_g,
                                                         W1r, W1o, b1, hbf, flags);
    k_gather2<<<G2BLK + UCBLK, 256, 0, stream>>>(dstoff, ddeg, glist,
                                                 (const ushortx8*)hbf,
                                                 W2r, W2o, b2, xs,
                                                 x_u, Wun, bun, flags);
    k_fc<<<1280, 256, 0, stream>>>(xs, cand, Wfc1, bfc1, Wfc2, bfc2, d_out, flags);
}